// Round 12
// baseline (289.900 us; speedup 1.0000x reference)
//
#include <hip/hip_runtime.h>
#include <hip/hip_bf16.h>
#include <math.h>

// ---- problem constants (fixed by setup_inputs) ----
#define B_N      8192
#define IN_DIM   784
#define KPAD     800        // 25 k-tiles of 32, zero-padded
#define HID      256
#define DL       8
#define NC       48
#define CH       64
#define NCLS     10
#define T_ITERS  5
#define TILES    128        // B_N / 64

#define DT_      0.12f
#define CLAMP_   3.0f
#define GAIN_    0.06f
// b = log2(e)/(2*sigma_i^2) = 0.50093578 ; sigma_e = sigma_i/2 -> E-exp = 4x I-exp.
#define SQIL2    0.70776814f
#define ONE_BF16 0x3F80u

#if defined(__has_builtin)
#if __has_builtin(__builtin_amdgcn_exp2f)
#define EXP2(x) __builtin_amdgcn_exp2f(x)
#endif
#endif
#ifndef EXP2
#define EXP2(x) exp2f(x)
#endif

typedef __attribute__((ext_vector_type(8))) short short8v;  // 8 bf16 (4 VGPRs)
typedef __attribute__((ext_vector_type(4))) float f32x4;    // MFMA C/D frag

__device__ __forceinline__ unsigned int pack_bf16_rhu(float lo, float hi) {
    unsigned int b0 = __builtin_bit_cast(unsigned int, lo);
    unsigned int b1 = __builtin_bit_cast(unsigned int, hi);
    return ((b0 + 0x8000u) >> 16) | ((b1 + 0x8000u) & 0xFFFF0000u);
}
__device__ __forceinline__ unsigned short bf16_1(float x) {
    return (unsigned short)((__builtin_bit_cast(unsigned int, x) + 0x8000u) >> 16);
}
__device__ __forceinline__ float bf16_to_f(unsigned short h) {
    return __builtin_bit_cast(float, ((unsigned int)h) << 16);
}

// split one z row (scaled) into hi/lo bf16 + c constant pair (lateral path)
__device__ __forceinline__ void z_split(const float4 a, const float4 b,
                                        uint4& Whi, uint4& Wlo, unsigned int& Wc)
{
    float u[8] = {SQIL2*a.x, SQIL2*a.y, SQIL2*a.z, SQIL2*a.w,
                  SQIL2*b.x, SQIL2*b.y, SQIL2*b.z, SQIL2*b.w};
    float sq = 0.f;
    #pragma unroll
    for (int d = 0; d < 8; ++d) sq = fmaf(u[d], u[d], sq);
    float cn = -0.5f * sq;
    unsigned short hi[8]; float lo[8];
    #pragma unroll
    for (int d = 0; d < 8; ++d) {
        hi[d] = bf16_1(u[d]);
        lo[d] = u[d] - bf16_to_f(hi[d]);
    }
    unsigned short ch_ = bf16_1(cn);
    unsigned short cl_ = bf16_1(cn - bf16_to_f(ch_));
    Whi.x = (unsigned int)hi[0] | ((unsigned int)hi[1] << 16);
    Whi.y = (unsigned int)hi[2] | ((unsigned int)hi[3] << 16);
    Whi.z = (unsigned int)hi[4] | ((unsigned int)hi[5] << 16);
    Whi.w = (unsigned int)hi[6] | ((unsigned int)hi[7] << 16);
    Wlo.x = pack_bf16_rhu(lo[0], lo[1]); Wlo.y = pack_bf16_rhu(lo[2], lo[3]);
    Wlo.z = pack_bf16_rhu(lo[4], lo[5]); Wlo.w = pack_bf16_rhu(lo[6], lo[7]);
    Wc = (unsigned int)ch_ | ((unsigned int)cl_ << 16);
}

// 3-term bf16 split of 8 f32 values (24 mantissa bits -> near-exact)
__device__ __forceinline__ void split3_8(const float v[8],
                                         uint4& Th, uint4& Tm, uint4& Tl)
{
    unsigned short h8[8], m8[8], l8[8];
    #pragma unroll
    for (int d = 0; d < 8; ++d) {
        unsigned short h = bf16_1(v[d]);
        float r1 = v[d] - bf16_to_f(h);
        unsigned short m = bf16_1(r1);
        float r2 = r1 - bf16_to_f(m);
        unsigned short l = bf16_1(r2);
        h8[d] = h; m8[d] = m; l8[d] = l;
    }
    Th.x = (unsigned int)h8[0] | ((unsigned int)h8[1] << 16);
    Th.y = (unsigned int)h8[2] | ((unsigned int)h8[3] << 16);
    Th.z = (unsigned int)h8[4] | ((unsigned int)h8[5] << 16);
    Th.w = (unsigned int)h8[6] | ((unsigned int)h8[7] << 16);
    Tm.x = (unsigned int)m8[0] | ((unsigned int)m8[1] << 16);
    Tm.y = (unsigned int)m8[2] | ((unsigned int)m8[3] << 16);
    Tm.z = (unsigned int)m8[4] | ((unsigned int)m8[5] << 16);
    Tm.w = (unsigned int)m8[6] | ((unsigned int)m8[7] << 16);
    Tl.x = (unsigned int)l8[0] | ((unsigned int)l8[1] << 16);
    Tl.y = (unsigned int)l8[2] | ((unsigned int)l8[3] << 16);
    Tl.z = (unsigned int)l8[4] | ((unsigned int)l8[5] << 16);
    Tl.w = (unsigned int)l8[6] | ((unsigned int)l8[7] << 16);
}

// ============ one-time: W1 -> transposed 3-term bf16, k padded to 800 ========
__global__ __launch_bounds__(256) void k_w1split(
    const float* __restrict__ W1, unsigned short* __restrict__ W1aT,
    unsigned short* __restrict__ W1bT, unsigned short* __restrict__ W1cT)
{
    const int k = blockIdx.x;        // 0..799
    const int n = threadIdx.x;       // 0..255
    float v = (k < IN_DIM) ? W1[(size_t)k * HID + n] : 0.f;
    unsigned short h = bf16_1(v);
    float r1 = v - bf16_to_f(h);
    unsigned short m = bf16_1(r1);
    unsigned short l = bf16_1(r1 - bf16_to_f(m));
    W1aT[(size_t)n * KPAD + k] = h;
    W1bT[(size_t)n * KPAD + k] = m;
    W1cT[(size_t)n * KPAD + k] = l;
}

// ============ encoder GEMM1 via MFMA (3-term bf16 split, f32 accum) ==========
__global__ __launch_bounds__(256, 2) void k_gemm1_tanh(
    const float* __restrict__ x, const unsigned short* __restrict__ W1aT,
    const unsigned short* __restrict__ W1bT, const unsigned short* __restrict__ W1cT,
    const float* __restrict__ b1, float* __restrict__ H1)
{
    __shared__ __align__(16) unsigned short Ah[2][64][40], Am[2][64][40], Al[2][64][40];
    __shared__ __align__(16) unsigned short Bh[2][64][40], Bm[2][64][40], Bl[2][64][40];
    const int tid = threadIdx.x;
    const int row0 = blockIdx.x * 64;
    const int col0 = blockIdx.y * 64;
    const int wv = tid >> 6, lane = tid & 63;
    const int l15 = lane & 15, g = lane >> 4;
    const int sr = tid >> 2, ss = tid & 3;   // staging: row/n = sr, 8-k seg = ss

    f32x4 acc[4] = {{0,0,0,0},{0,0,0,0},{0,0,0,0},{0,0,0,0}};

    // prologue: tile 0 -> buf 0
    {
        float xv[8];
        {
            const float* xp = x + (size_t)(row0 + sr) * IN_DIM + ss * 8;
            float4 a = *(const float4*)(xp), b = *(const float4*)(xp + 4);
            xv[0]=a.x; xv[1]=a.y; xv[2]=a.z; xv[3]=a.w;
            xv[4]=b.x; xv[5]=b.y; xv[6]=b.z; xv[7]=b.w;
        }
        uint4 Th, Tm, Tl;
        split3_8(xv, Th, Tm, Tl);
        *(uint4*)&Ah[0][sr][ss * 8] = Th;
        *(uint4*)&Am[0][sr][ss * 8] = Tm;
        *(uint4*)&Al[0][sr][ss * 8] = Tl;
        const size_t wo = (size_t)(col0 + sr) * KPAD + ss * 8;
        *(uint4*)&Bh[0][sr][ss * 8] = *(const uint4*)(W1aT + wo);
        *(uint4*)&Bm[0][sr][ss * 8] = *(const uint4*)(W1bT + wo);
        *(uint4*)&Bl[0][sr][ss * 8] = *(const uint4*)(W1cT + wo);
    }

    const int NK = KPAD / 32;   // 25
    #pragma unroll 1
    for (int ks = 0; ks < NK; ++ks) {
        const int cur = ks & 1;
        const bool more = (ks + 1 < NK);
        float xv[8];
        uint4 wa4, wb4, wc4;
        if (more) {
            const int k0 = (ks + 1) * 32;
            if (k0 + ss * 8 < IN_DIM) {
                const float* xp = x + (size_t)(row0 + sr) * IN_DIM + k0 + ss * 8;
                float4 a = *(const float4*)(xp), b = *(const float4*)(xp + 4);
                xv[0]=a.x; xv[1]=a.y; xv[2]=a.z; xv[3]=a.w;
                xv[4]=b.x; xv[5]=b.y; xv[6]=b.z; xv[7]=b.w;
            } else {
                #pragma unroll
                for (int d = 0; d < 8; ++d) xv[d] = 0.f;
            }
            const size_t wo = (size_t)(col0 + sr) * KPAD + k0 + ss * 8;
            wa4 = *(const uint4*)(W1aT + wo);
            wb4 = *(const uint4*)(W1bT + wo);
            wc4 = *(const uint4*)(W1cT + wo);
        }
        __syncthreads();   // buffer[cur] fully written

        short8v ah = *(const short8v*)&Ah[cur][16 * wv + l15][g * 8];
        short8v am = *(const short8v*)&Am[cur][16 * wv + l15][g * 8];
        short8v al = *(const short8v*)&Al[cur][16 * wv + l15][g * 8];
        __builtin_amdgcn_s_setprio(1);
        #pragma unroll
        for (int nt = 0; nt < 4; ++nt) {
            short8v bh = *(const short8v*)&Bh[cur][nt * 16 + l15][g * 8];
            short8v bm = *(const short8v*)&Bm[cur][nt * 16 + l15][g * 8];
            short8v bl = *(const short8v*)&Bl[cur][nt * 16 + l15][g * 8];
            acc[nt] = __builtin_amdgcn_mfma_f32_16x16x32_bf16(ah, bh, acc[nt], 0, 0, 0);
            acc[nt] = __builtin_amdgcn_mfma_f32_16x16x32_bf16(am, bh, acc[nt], 0, 0, 0);
            acc[nt] = __builtin_amdgcn_mfma_f32_16x16x32_bf16(ah, bm, acc[nt], 0, 0, 0);
            acc[nt] = __builtin_amdgcn_mfma_f32_16x16x32_bf16(al, bh, acc[nt], 0, 0, 0);
            acc[nt] = __builtin_amdgcn_mfma_f32_16x16x32_bf16(am, bm, acc[nt], 0, 0, 0);
            acc[nt] = __builtin_amdgcn_mfma_f32_16x16x32_bf16(ah, bl, acc[nt], 0, 0, 0);
        }
        __builtin_amdgcn_s_setprio(0);

        if (more) {   // write next tile into other buffer (no 2nd barrier)
            const int nb = cur ^ 1;
            uint4 Th, Tm, Tl;
            split3_8(xv, Th, Tm, Tl);
            *(uint4*)&Ah[nb][sr][ss * 8] = Th;
            *(uint4*)&Am[nb][sr][ss * 8] = Tm;
            *(uint4*)&Al[nb][sr][ss * 8] = Tl;
            *(uint4*)&Bh[nb][sr][ss * 8] = wa4;
            *(uint4*)&Bm[nb][sr][ss * 8] = wb4;
            *(uint4*)&Bl[nb][sr][ss * 8] = wc4;
        }
    }

    // epilogue: D[g*4+r][l15] per n-tile
    #pragma unroll
    for (int nt = 0; nt < 4; ++nt) {
        const int cc = col0 + nt * 16 + l15;
        const float bc = b1[cc];
        #pragma unroll
        for (int r = 0; r < 4; ++r) {
            const int rr = row0 + 16 * wv + g * 4 + r;
            H1[(size_t)rr * HID + cc] = tanhf(acc[nt][r] + bc);
        }
    }
}

// ============ GEMM2: z0 = H1 @ W2 + b2 ============
__global__ __launch_bounds__(256) void k_gemm2(
    const float* __restrict__ H1, const float* __restrict__ W2,
    const float* __restrict__ b2, float* __restrict__ zbuf)
{
    __shared__ float W2s[HID][DL];
    const int tid = threadIdx.x;
    for (int l = tid; l < HID * DL; l += 256) W2s[l >> 3][l & 7] = W2[l];
    __syncthreads();
    const int row = blockIdx.x * 32 + (tid >> 3);
    const int d = tid & 7;
    float acc = b2[d];
    const float* hr = H1 + (size_t)row * HID;
    for (int k = 0; k < HID; k += 4) {
        float4 hv = *(const float4*)(hr + k);
        acc += hv.x * W2s[k][d] + hv.y * W2s[k+1][d]
             + hv.z * W2s[k+2][d] + hv.w * W2s[k+3][d];
    }
    zbuf[(size_t)row * DL + d] = acc;
}

// ============ PM field (4 steps) + fused partial-reduce + proj h-update ======
// 16 lanes/row (3 centers/lane). Exact IEEE sqrt/divide in the stiff flow.
template<int S, bool HP>
__global__ __launch_bounds__(256) void k_pm_proj(
    const float* __restrict__ centers, const float* __restrict__ mus,
    const float* __restrict__ projW, const float* __restrict__ projb,
    float* __restrict__ zbuf, float* __restrict__ hB,
    unsigned short* __restrict__ hTb,
    const float* __restrict__ pAcc, const float* __restrict__ pDen)
{
    __shared__ float4 cs4[NC][2];
    __shared__ float mu_s[NC];
    __shared__ float pW[DL][CH];
    __shared__ float pb[CH];
    const int tid = threadIdx.x;
    for (int l = tid; l < NC * 2; l += 256) cs4[l >> 1][l & 1] = ((const float4*)centers)[l];
    if (tid < NC) mu_s[tid] = mus[tid];
    for (int l = tid; l < DL * CH; l += 256) pW[l >> 6][l & 63] = projW[l];
    if (tid < CH) pb[tid] = projb[tid];
    __syncthreads();

    const int rloc = tid >> 4;
    const int ln   = tid & 15;
    const int row  = blockIdx.x * 16 + rloc;

    float4 cza[3], czb[3];
    float mur[3];
    #pragma unroll
    for (int k = 0; k < 3; ++k) {
        cza[k] = cs4[ln + 16*k][0];
        czb[k] = cs4[ln + 16*k][1];
        mur[k] = mu_s[ln + 16*k];
    }

    float z[8];
    {
        const float4* zp = (const float4*)(zbuf + (size_t)row * DL);
        float4 a = zp[0], b = zp[1];
        z[0]=a.x; z[1]=a.y; z[2]=a.z; z[3]=a.w;
        z[4]=b.x; z[5]=b.y; z[6]=b.z; z[7]=b.w;
    }

    #pragma unroll
    for (int step = 0; step < 4; ++step) {
        float np = 0.f;
        float gp[8] = {0,0,0,0,0,0,0,0};
        #pragma unroll
        for (int k = 0; k < 3; ++k) {
            float d0 = z[0]-cza[k].x, d1 = z[1]-cza[k].y;
            float d2 = z[2]-cza[k].z, d3 = z[3]-cza[k].w;
            float d4 = z[4]-czb[k].x, d5 = z[5]-czb[k].y;
            float d6 = z[6]-czb[k].z, d7 = z[7]-czb[k].w;
            float r2 = 1e-4f;
            r2 = fmaf(d0,d0,r2); r2 = fmaf(d1,d1,r2);
            r2 = fmaf(d2,d2,r2); r2 = fmaf(d3,d3,r2);
            r2 = fmaf(d4,d4,r2); r2 = fmaf(d5,d5,r2);
            r2 = fmaf(d6,d6,r2); r2 = fmaf(d7,d7,r2);
            float r = sqrtf(r2);
            float mr = mur[k] / r;
            np += mr;
            float t = mr / r2;
            gp[0] = fmaf(-t, d0, gp[0]); gp[1] = fmaf(-t, d1, gp[1]);
            gp[2] = fmaf(-t, d2, gp[2]); gp[3] = fmaf(-t, d3, gp[3]);
            gp[4] = fmaf(-t, d4, gp[4]); gp[5] = fmaf(-t, d5, gp[5]);
            gp[6] = fmaf(-t, d6, gp[6]); gp[7] = fmaf(-t, d7, gp[7]);
        }
        #pragma unroll
        for (int m = 1; m < 16; m <<= 1) {
            np += __shfl_xor(np, m);
            #pragma unroll
            for (int d = 0; d < 8; ++d) gp[d] += __shfl_xor(gp[d], m);
        }
        float s = DT_ / (1.f + np);
        #pragma unroll
        for (int d = 0; d < 8; ++d) {
            z[d] = fmaf(s, gp[d], z[d]);
            z[d] = fminf(fmaxf(z[d], -CLAMP_), CLAMP_);
        }
    }

    if (ln < 8) {
        float zout = z[0];
        #pragma unroll
        for (int d = 1; d < 8; ++d) zout = (ln == d) ? z[d] : zout;
        zbuf[(size_t)row * DL + ln] = zout;
    }

    const int c0 = ln * 4;
    float hin[4];
    if (HP) {
        float den = 1e-6f;
        #pragma unroll
        for (int s = 0; s < S; ++s) den += pDen[s * B_N + row];
        float inv = GAIN_ / den;
        float4 a = {0.f, 0.f, 0.f, 0.f};
        #pragma unroll
        for (int s = 0; s < S; ++s) {
            float4 p = *(const float4*)(pAcc + (size_t)s * B_N * CH
                                        + (size_t)row * CH + c0);
            a.x += p.x; a.y += p.y; a.z += p.z; a.w += p.w;
        }
        float4 hm = *(const float4*)(hB + (size_t)row * CH + c0);
        hin[0] = fmaf(inv, a.x, hm.x);
        hin[1] = fmaf(inv, a.y, hm.y);
        hin[2] = fmaf(inv, a.z, hm.z);
        hin[3] = fmaf(inv, a.w, hm.w);
    } else {
        #pragma unroll
        for (int k = 0; k < 4; ++k) hin[k] = 0.f;
    }
    #pragma unroll
    for (int k = 0; k < 4; ++k) {
        int c = c0 + k;
        float s = pb[c];
        #pragma unroll
        for (int dd = 0; dd < DL; ++dd) s = fmaf(z[dd], pW[dd][c], s);
        hin[k] = 0.9f * hin[k] + 0.1f * tanhf(s);
    }
    float4 o0 = {hin[0], hin[1], hin[2], hin[3]};
    *(float4*)(hB + (size_t)row * CH + c0) = o0;

    {
        const int jl = row & 63;
        const int colp = (jl & 35) | ((jl & 12) << 1) | ((jl & 16) >> 2);
        const size_t tb = (size_t)(row & ~63) + colp;
        #pragma unroll
        for (int k = 0; k < 4; ++k)
            hTb[(size_t)(c0 + k) * B_N + tb] = bf16_1(hin[k]);
    }
}

// ============ lateral EI: Gram-MFMA weights + MFMA K@h ============
template<int S>
__global__ __launch_bounds__(256, 4) void k_lateral(
    const float* __restrict__ zbuf, const unsigned short* __restrict__ hTb,
    float* __restrict__ pAcc, float* __restrict__ pDen)
{
    __shared__ __align__(16) unsigned short zA[2][64 * 24];
    __shared__ __align__(16) unsigned short hsT[2][CH][72];
    const int tid  = threadIdx.x;
    const int lane = tid & 63;
    const int wv   = tid >> 6;
    const int l15  = lane & 15;
    const int g    = lane >> 4;
    const int rowbase = blockIdx.x * 64;
    const int t0 = (TILES * blockIdx.y) / S;
    const int t1 = (TILES * (blockIdx.y + 1)) / S;
    const int chS = tid >> 2, segS = tid & 3;

    short8v bZ;
    {
        const int irow = rowbase + 16 * wv + l15;
        const float4* zp = (const float4*)(zbuf + (size_t)irow * DL);
        uint4 Whi, Wlo; unsigned int Wc;
        z_split(zp[0], zp[1], Whi, Wlo, Wc);
        union { unsigned int u[4]; short8v v; } uh, ul, ua;
        uh.u[0]=Whi.x; uh.u[1]=Whi.y; uh.u[2]=Whi.z; uh.u[3]=Whi.w;
        ul.u[0]=Wlo.x; ul.u[1]=Wlo.y; ul.u[2]=Wlo.z; ul.u[3]=Wlo.w;
        ua.u[0] = ONE_BF16 | (ONE_BF16 << 16);
        ua.u[1] = Wc; ua.u[2] = 0; ua.u[3] = 0;
        bZ = (g == 2) ? ul.v : ((g == 3) ? ua.v : uh.v);
    }
    const int offsh = (g == 1) ? 8 : ((g == 3) ? 16 : 0);

    short8v bones;
    {
        union { unsigned int u[4]; short8v v; } uo;
        uo.u[0] = uo.u[1] = uo.u[2] = uo.u[3] = ONE_BF16 | (ONE_BF16 << 16);
        bones = uo.v;
    }

    f32x4 acc0 = {0,0,0,0}, acc1 = {0,0,0,0}, acc2 = {0,0,0,0}, acc3 = {0,0,0,0};
    f32x4 acc4 = {0,0,0,0};
    const f32x4 zc = {0,0,0,0};

    {
        const int jb = t0 * 64;
        if (tid < 64) {
            const float4* zp = (const float4*)(zbuf + (size_t)(jb + tid) * DL);
            uint4 Whi, Wlo; unsigned int Wc;
            z_split(zp[0], zp[1], Whi, Wlo, Wc);
            uint4 W2v; W2v.x = Wc; W2v.y = ONE_BF16 | (ONE_BF16 << 16);
            W2v.z = 0; W2v.w = 0;
            unsigned short* dst = &zA[0][tid * 24];
            *(uint4*)(dst)      = Whi;
            *(uint4*)(dst + 8)  = Wlo;
            *(uint4*)(dst + 16) = W2v;
        }
        const unsigned short* hs = hTb + (size_t)chS * B_N + jb + segS * 16;
        *(uint4*)(&hsT[0][chS][segS * 16])     = *(const uint4*)(hs);
        *(uint4*)(&hsT[0][chS][segS * 16 + 8]) = *(const uint4*)(hs + 8);
    }

    #pragma unroll 1
    for (int jt = t0; jt < t1; ++jt) {
        const int cur = (jt - t0) & 1;
        const bool more = (jt + 1 < t1);
        uint4 h0n, h1n;
        float4 zna, znb;
        if (more) {
            const int jb2 = (jt + 1) * 64;
            const unsigned short* hs = hTb + (size_t)chS * B_N + jb2 + segS * 16;
            h0n = *(const uint4*)(hs);
            h1n = *(const uint4*)(hs + 8);
            if (tid < 64) {
                const float4* zp = (const float4*)(zbuf + (size_t)(jb2 + tid) * DL);
                zna = zp[0]; znb = zp[1];
            }
        }
        __syncthreads();

        f32x4 gac[4];
        __builtin_amdgcn_s_setprio(1);
        #pragma unroll
        for (int t = 0; t < 4; ++t) {
            short8v az = *(const short8v*)(&zA[cur][(t * 16 + l15) * 24 + offsh]);
            gac[t] = __builtin_amdgcn_mfma_f32_16x16x32_bf16(az, bZ, zc, 0, 0, 0);
        }
        __builtin_amdgcn_s_setprio(0);

        short8v afr[2];
        #pragma unroll
        for (int kb = 0; kb < 2; ++kb) {
            float w8[8];
            #pragma unroll
            for (int m = 0; m < 8; ++m) {
                float out = gac[2 * kb + (m >> 2)][m & 3];
                float e1 = EXP2(out);
                float e2 = e1 * e1;
                float e4 = e2 * e2;
                float e8 = e4 * e4;
                w8[m] = fmaf(0.8f, e8, -e2);
            }
            union { unsigned int u[4]; short8v v; } uf;
            uf.u[0] = pack_bf16_rhu(w8[0], w8[1]);
            uf.u[1] = pack_bf16_rhu(w8[2], w8[3]);
            uf.u[2] = pack_bf16_rhu(w8[4], w8[5]);
            uf.u[3] = pack_bf16_rhu(w8[6], w8[7]);
            afr[kb] = uf.v;
        }

        __builtin_amdgcn_s_setprio(1);
        #pragma unroll
        for (int kb = 0; kb < 2; ++kb) {
            const int jo = kb * 32 + g * 8;
            short8v b0 = *(const short8v*)&hsT[cur][ 0 + l15][jo];
            short8v b1 = *(const short8v*)&hsT[cur][16 + l15][jo];
            short8v b2 = *(const short8v*)&hsT[cur][32 + l15][jo];
            short8v b3 = *(const short8v*)&hsT[cur][48 + l15][jo];
            acc0 = __builtin_amdgcn_mfma_f32_16x16x32_bf16(afr[kb], b0, acc0, 0, 0, 0);
            acc1 = __builtin_amdgcn_mfma_f32_16x16x32_bf16(afr[kb], b1, acc1, 0, 0, 0);
            acc2 = __builtin_amdgcn_mfma_f32_16x16x32_bf16(afr[kb], b2, acc2, 0, 0, 0);
            acc3 = __builtin_amdgcn_mfma_f32_16x16x32_bf16(afr[kb], b3, acc3, 0, 0, 0);
            acc4 = __builtin_amdgcn_mfma_f32_16x16x32_bf16(afr[kb], bones, acc4, 0, 0, 0);
        }
        __builtin_amdgcn_s_setprio(0);

        if (more) {
            const int nb = cur ^ 1;
            if (tid < 64) {
                uint4 Whi, Wlo; unsigned int Wc;
                z_split(zna, znb, Whi, Wlo, Wc);
                uint4 W2v; W2v.x = Wc; W2v.y = ONE_BF16 | (ONE_BF16 << 16);
                W2v.z = 0; W2v.w = 0;
                unsigned short* dst = &zA[nb][tid * 24];
                *(uint4*)(dst)      = Whi;
                *(uint4*)(dst + 8)  = Wlo;
                *(uint4*)(dst + 16) = W2v;
            }
            *(uint4*)(&hsT[nb][chS][segS * 16])     = h0n;
            *(uint4*)(&hsT[nb][chS][segS * 16 + 8]) = h1n;
        }
    }

    float* pA = pAcc + (size_t)blockIdx.y * (B_N * CH) + (size_t)rowbase * CH;
    #pragma unroll
    for (int r = 0; r < 4; ++r) {
        int gi = 16 * wv + g * 4 + r;
        pA[(size_t)gi * CH +  0 + l15] = acc0[r];
        pA[(size_t)gi * CH + 16 + l15] = acc1[r];
        pA[(size_t)gi * CH + 32 + l15] = acc2[r];
        pA[(size_t)gi * CH + 48 + l15] = acc3[r];
    }
    if (l15 == 0) {
        #pragma unroll
        for (int r = 0; r < 4; ++r)
            pDen[blockIdx.y * B_N + rowbase + 16 * wv + g * 4 + r] = acc4[r];
    }
}

// ============ final: h = hmid + GAIN*acc/den ; logits = h @ roW + rob ======
template<int S>
__global__ __launch_bounds__(256) void k_logits_h(
    const float* __restrict__ hmid, const float* __restrict__ pAcc,
    const float* __restrict__ pDen, const float* __restrict__ roW,
    const float* __restrict__ rob, float* __restrict__ out_logits,
    float* __restrict__ out_h)
{
    __shared__ float hsh[64][68];
    __shared__ float ro[CH][NCLS];
    __shared__ float rb[NCLS];
    const int tid = threadIdx.x;
    for (int l = tid; l < CH * NCLS; l += 256) ro[l / NCLS][l % NCLS] = roW[l];
    if (tid < NCLS) rb[tid] = rob[tid];
    const int rowbase = blockIdx.x * 64;
    const int r  = tid >> 2;
    const int c0 = (tid & 3) * 16;
    const int row = rowbase + r;
    float den = 1e-6f;
    #pragma unroll
    for (int s = 0; s < S; ++s) den += pDen[s * B_N + row];
    float inv = GAIN_ / den;
    #pragma unroll
    for (int q = 0; q < 4; ++q) {
        float4 a = {0.f, 0.f, 0.f, 0.f};
        #pragma unroll
        for (int s = 0; s < S; ++s) {
            float4 p = *(const float4*)(pAcc + (size_t)s * B_N * CH
                                        + (size_t)row * CH + c0 + q * 4);
            a.x += p.x; a.y += p.y; a.z += p.z; a.w += p.w;
        }
        float4 hm = *(const float4*)(hmid + (size_t)row * CH + c0 + q * 4);
        float4 hv;
        hv.x = fmaf(inv, a.x, hm.x); hv.y = fmaf(inv, a.y, hm.y);
        hv.z = fmaf(inv, a.z, hm.z); hv.w = fmaf(inv, a.w, hm.w);
        *(float4*)(&hsh[r][c0 + q * 4]) = hv;
        *(float4*)(out_h + (size_t)row * CH + c0 + q * 4) = hv;
    }
    __syncthreads();
    for (int idx = tid; idx < 64 * NCLS; idx += 256) {
        int rr = idx / NCLS, o = idx % NCLS;
        float s = rb[o];
        #pragma unroll
        for (int k = 0; k < CH; ++k) s = fmaf(hsh[rr][k], ro[k][o], s);
        out_logits[(size_t)(rowbase + rr) * NCLS + o] = s;
    }
}

// ---- per-split launch helper ----
template<int S>
static void run_all(const float* x, const float* W1, const float* b1,
                    const float* W2, const float* b2, const float* centers,
                    const float* mus, const float* projW, const float* projb,
                    const float* roW, const float* rob,
                    float* ws, float* out, hipStream_t stream)
{
    float* pAcc = ws;
    float* pDen = ws + (size_t)S * B_N * CH;
    float* zbuf = pDen + (size_t)S * B_N;
    float* hB   = zbuf + B_N * DL;
    unsigned short* hTb  = (unsigned short*)(hB + B_N * CH);   // B_N*CH bf16
    unsigned short* W1aT = hTb + (size_t)B_N * CH;             // 256*800
    unsigned short* W1bT = W1aT + (size_t)HID * KPAD;
    unsigned short* W1cT = W1bT + (size_t)HID * KPAD;
    float* H1   = ws;   // pre-loop only; fits under pAcc (S >= 4)

    float* out_logits = out;
    float* out_z      = out + 81920;
    float* out_h      = out_z + 65536;

    k_w1split<<<KPAD, HID, 0, stream>>>(W1, W1aT, W1bT, W1cT);
    k_gemm1_tanh<<<dim3(B_N / 64, HID / 64), 256, 0, stream>>>(x, W1aT, W1bT, W1cT, b1, H1);
    k_gemm2<<<B_N / 32, 256, 0, stream>>>(H1, W2, b2, zbuf);

    for (int t = 0; t < T_ITERS; ++t) {
        if (t == 0)
            k_pm_proj<S, false><<<B_N / 16, 256, 0, stream>>>(
                centers, mus, projW, projb, zbuf, hB, hTb, pAcc, pDen);
        else
            k_pm_proj<S, true><<<B_N / 16, 256, 0, stream>>>(
                centers, mus, projW, projb, zbuf, hB, hTb, pAcc, pDen);
        k_lateral<S><<<dim3(TILES, S), 256, 0, stream>>>(zbuf, hTb, pAcc, pDen);
    }

    k_logits_h<S><<<TILES, 256, 0, stream>>>(hB, pAcc, pDen, roW, rob,
                                             out_logits, out_h);
    hipMemcpyAsync(out_z, zbuf, (size_t)B_N * DL * sizeof(float),
                   hipMemcpyDeviceToDevice, stream);
}

extern "C" void kernel_launch(void* const* d_in, const int* in_sizes, int n_in,
                              void* d_out, int out_size, void* d_ws, size_t ws_size,
                              hipStream_t stream)
{
    const float* x       = (const float*)d_in[0];
    const float* W1      = (const float*)d_in[1];
    const float* b1      = (const float*)d_in[2];
    const float* W2      = (const float*)d_in[3];
    const float* b2      = (const float*)d_in[4];
    const float* centers = (const float*)d_in[5];
    const float* mus     = (const float*)d_in[6];
    const float* projW   = (const float*)d_in[7];
    const float* projb   = (const float*)d_in[8];
    const float* roW     = (const float*)d_in[9];
    const float* rob     = (const float*)d_in[10];

    float* ws  = (float*)d_ws;
    float* out = (float*)d_out;

    // floats: S*B_N*CH + S*B_N + B_N*DL + B_N*CH + B_N*CH/2 (hTb) + 3*HID*KPAD/2 (W1 split)
    const size_t extraW  = (size_t)3 * HID * KPAD / 2;
    const size_t needS12 = ((size_t)12*B_N*CH + 12*B_N + B_N*DL + B_N*CH + B_N*CH/2 + extraW) * 4;
    const size_t needS8  = ((size_t) 8*B_N*CH +  8*B_N + B_N*DL + B_N*CH + B_N*CH/2 + extraW) * 4;
    const size_t needS4  = ((size_t) 4*B_N*CH +  4*B_N + B_N*DL + B_N*CH + B_N*CH/2 + extraW) * 4;

    if (ws_size >= needS12)
        run_all<12>(x, W1, b1, W2, b2, centers, mus, projW, projb, roW, rob, ws, out, stream);
    else if (ws_size >= needS8)
        run_all<8>(x, W1, b1, W2, b2, centers, mus, projW, projb, roW, rob, ws, out, stream);
    else if (ws_size >= needS4)
        run_all<4>(x, W1, b1, W2, b2, centers, mus, projW, projb, roW, rob, ws, out, stream);
    else
        run_all<2>(x, W1, b1, W2, b2, centers, mus, projW, projb, roW, rob, ws, out, stream);
}

// Round 13
// 267.795 us; speedup vs baseline: 1.0825x; 1.0825x over previous
//
#include <hip/hip_runtime.h>
#include <hip/hip_bf16.h>
#include <math.h>

// ---- problem constants (fixed by setup_inputs) ----
#define B_N      8192
#define IN_DIM   784
#define KPAD     800        // 25 k-tiles of 32, zero-padded
#define HID      256
#define DL       8
#define NC       48
#define CH       64
#define NCLS     10
#define T_ITERS  5
#define TILES    128        // B_N / 64

#define DT_      0.12f
#define CLAMP_   3.0f
#define GAIN_    0.06f
// b = log2(e)/(2*sigma_i^2) = 0.50093578 ; sigma_e = sigma_i/2 -> E-exp = 4x I-exp.
#define SQIL2    0.70776814f
#define ONE_BF16 0x3F80u

#if defined(__has_builtin)
#if __has_builtin(__builtin_amdgcn_exp2f)
#define EXP2(x) __builtin_amdgcn_exp2f(x)
#endif
#endif
#ifndef EXP2
#define EXP2(x) exp2f(x)
#endif

typedef __attribute__((ext_vector_type(8))) short short8v;  // 8 bf16 (4 VGPRs)
typedef __attribute__((ext_vector_type(4))) float f32x4;    // MFMA C/D frag

__device__ __forceinline__ unsigned int pack_bf16_rhu(float lo, float hi) {
    unsigned int b0 = __builtin_bit_cast(unsigned int, lo);
    unsigned int b1 = __builtin_bit_cast(unsigned int, hi);
    return ((b0 + 0x8000u) >> 16) | ((b1 + 0x8000u) & 0xFFFF0000u);
}
__device__ __forceinline__ unsigned short bf16_1(float x) {
    return (unsigned short)((__builtin_bit_cast(unsigned int, x) + 0x8000u) >> 16);
}
__device__ __forceinline__ float bf16_to_f(unsigned short h) {
    return __builtin_bit_cast(float, ((unsigned int)h) << 16);
}

// split one z row (scaled) into hi/lo bf16 + c constant pair (lateral path)
__device__ __forceinline__ void z_split(const float4 a, const float4 b,
                                        uint4& Whi, uint4& Wlo, unsigned int& Wc)
{
    float u[8] = {SQIL2*a.x, SQIL2*a.y, SQIL2*a.z, SQIL2*a.w,
                  SQIL2*b.x, SQIL2*b.y, SQIL2*b.z, SQIL2*b.w};
    float sq = 0.f;
    #pragma unroll
    for (int d = 0; d < 8; ++d) sq = fmaf(u[d], u[d], sq);
    float cn = -0.5f * sq;
    unsigned short hi[8]; float lo[8];
    #pragma unroll
    for (int d = 0; d < 8; ++d) {
        hi[d] = bf16_1(u[d]);
        lo[d] = u[d] - bf16_to_f(hi[d]);
    }
    unsigned short ch_ = bf16_1(cn);
    unsigned short cl_ = bf16_1(cn - bf16_to_f(ch_));
    Whi.x = (unsigned int)hi[0] | ((unsigned int)hi[1] << 16);
    Whi.y = (unsigned int)hi[2] | ((unsigned int)hi[3] << 16);
    Whi.z = (unsigned int)hi[4] | ((unsigned int)hi[5] << 16);
    Whi.w = (unsigned int)hi[6] | ((unsigned int)hi[7] << 16);
    Wlo.x = pack_bf16_rhu(lo[0], lo[1]); Wlo.y = pack_bf16_rhu(lo[2], lo[3]);
    Wlo.z = pack_bf16_rhu(lo[4], lo[5]); Wlo.w = pack_bf16_rhu(lo[6], lo[7]);
    Wc = (unsigned int)ch_ | ((unsigned int)cl_ << 16);
}

// 3-term bf16 split of 8 f32 values (24 mantissa bits -> near-exact)
__device__ __forceinline__ void split3_8(const float v[8],
                                         uint4& Th, uint4& Tm, uint4& Tl)
{
    unsigned short h8[8], m8[8], l8[8];
    #pragma unroll
    for (int d = 0; d < 8; ++d) {
        unsigned short h = bf16_1(v[d]);
        float r1 = v[d] - bf16_to_f(h);
        unsigned short m = bf16_1(r1);
        float r2 = r1 - bf16_to_f(m);
        unsigned short l = bf16_1(r2);
        h8[d] = h; m8[d] = m; l8[d] = l;
    }
    Th.x = (unsigned int)h8[0] | ((unsigned int)h8[1] << 16);
    Th.y = (unsigned int)h8[2] | ((unsigned int)h8[3] << 16);
    Th.z = (unsigned int)h8[4] | ((unsigned int)h8[5] << 16);
    Th.w = (unsigned int)h8[6] | ((unsigned int)h8[7] << 16);
    Tm.x = (unsigned int)m8[0] | ((unsigned int)m8[1] << 16);
    Tm.y = (unsigned int)m8[2] | ((unsigned int)m8[3] << 16);
    Tm.z = (unsigned int)m8[4] | ((unsigned int)m8[5] << 16);
    Tm.w = (unsigned int)m8[6] | ((unsigned int)m8[7] << 16);
    Tl.x = (unsigned int)l8[0] | ((unsigned int)l8[1] << 16);
    Tl.y = (unsigned int)l8[2] | ((unsigned int)l8[3] << 16);
    Tl.z = (unsigned int)l8[4] | ((unsigned int)l8[5] << 16);
    Tl.w = (unsigned int)l8[6] | ((unsigned int)l8[7] << 16);
}

// ============ one-time: W1 -> transposed 3-term bf16, k padded to 800 ========
__global__ __launch_bounds__(256) void k_w1split(
    const float* __restrict__ W1, unsigned short* __restrict__ W1aT,
    unsigned short* __restrict__ W1bT, unsigned short* __restrict__ W1cT)
{
    const int k = blockIdx.x;        // 0..799
    const int n = threadIdx.x;       // 0..255
    float v = (k < IN_DIM) ? W1[(size_t)k * HID + n] : 0.f;
    unsigned short h = bf16_1(v);
    float r1 = v - bf16_to_f(h);
    unsigned short m = bf16_1(r1);
    unsigned short l = bf16_1(r1 - bf16_to_f(m));
    W1aT[(size_t)n * KPAD + k] = h;
    W1bT[(size_t)n * KPAD + k] = m;
    W1cT[(size_t)n * KPAD + k] = l;
}

// ============ encoder GEMM1 via MFMA (3-term bf16 split, f32 accum) ==========
__global__ __launch_bounds__(256, 2) void k_gemm1_tanh(
    const float* __restrict__ x, const unsigned short* __restrict__ W1aT,
    const unsigned short* __restrict__ W1bT, const unsigned short* __restrict__ W1cT,
    const float* __restrict__ b1, float* __restrict__ H1)
{
    __shared__ __align__(16) unsigned short Ah[2][64][40], Am[2][64][40], Al[2][64][40];
    __shared__ __align__(16) unsigned short Bh[2][64][40], Bm[2][64][40], Bl[2][64][40];
    const int tid = threadIdx.x;
    const int row0 = blockIdx.x * 64;
    const int col0 = blockIdx.y * 64;
    const int wv = tid >> 6, lane = tid & 63;
    const int l15 = lane & 15, g = lane >> 4;
    const int sr = tid >> 2, ss = tid & 3;   // staging: row/n = sr, 8-k seg = ss

    f32x4 acc[4] = {{0,0,0,0},{0,0,0,0},{0,0,0,0},{0,0,0,0}};

    // prologue: tile 0 -> buf 0
    {
        float xv[8];
        {
            const float* xp = x + (size_t)(row0 + sr) * IN_DIM + ss * 8;
            float4 a = *(const float4*)(xp), b = *(const float4*)(xp + 4);
            xv[0]=a.x; xv[1]=a.y; xv[2]=a.z; xv[3]=a.w;
            xv[4]=b.x; xv[5]=b.y; xv[6]=b.z; xv[7]=b.w;
        }
        uint4 Th, Tm, Tl;
        split3_8(xv, Th, Tm, Tl);
        *(uint4*)&Ah[0][sr][ss * 8] = Th;
        *(uint4*)&Am[0][sr][ss * 8] = Tm;
        *(uint4*)&Al[0][sr][ss * 8] = Tl;
        const size_t wo = (size_t)(col0 + sr) * KPAD + ss * 8;
        *(uint4*)&Bh[0][sr][ss * 8] = *(const uint4*)(W1aT + wo);
        *(uint4*)&Bm[0][sr][ss * 8] = *(const uint4*)(W1bT + wo);
        *(uint4*)&Bl[0][sr][ss * 8] = *(const uint4*)(W1cT + wo);
    }

    const int NK = KPAD / 32;   // 25
    #pragma unroll 1
    for (int ks = 0; ks < NK; ++ks) {
        const int cur = ks & 1;
        const bool more = (ks + 1 < NK);
        float xv[8];
        uint4 wa4, wb4, wc4;
        if (more) {
            const int k0 = (ks + 1) * 32;
            if (k0 + ss * 8 < IN_DIM) {
                const float* xp = x + (size_t)(row0 + sr) * IN_DIM + k0 + ss * 8;
                float4 a = *(const float4*)(xp), b = *(const float4*)(xp + 4);
                xv[0]=a.x; xv[1]=a.y; xv[2]=a.z; xv[3]=a.w;
                xv[4]=b.x; xv[5]=b.y; xv[6]=b.z; xv[7]=b.w;
            } else {
                #pragma unroll
                for (int d = 0; d < 8; ++d) xv[d] = 0.f;
            }
            const size_t wo = (size_t)(col0 + sr) * KPAD + k0 + ss * 8;
            wa4 = *(const uint4*)(W1aT + wo);
            wb4 = *(const uint4*)(W1bT + wo);
            wc4 = *(const uint4*)(W1cT + wo);
        }
        __syncthreads();   // buffer[cur] fully written

        short8v ah = *(const short8v*)&Ah[cur][16 * wv + l15][g * 8];
        short8v am = *(const short8v*)&Am[cur][16 * wv + l15][g * 8];
        short8v al = *(const short8v*)&Al[cur][16 * wv + l15][g * 8];
        __builtin_amdgcn_s_setprio(1);
        #pragma unroll
        for (int nt = 0; nt < 4; ++nt) {
            short8v bh = *(const short8v*)&Bh[cur][nt * 16 + l15][g * 8];
            short8v bm = *(const short8v*)&Bm[cur][nt * 16 + l15][g * 8];
            short8v bl = *(const short8v*)&Bl[cur][nt * 16 + l15][g * 8];
            acc[nt] = __builtin_amdgcn_mfma_f32_16x16x32_bf16(ah, bh, acc[nt], 0, 0, 0);
            acc[nt] = __builtin_amdgcn_mfma_f32_16x16x32_bf16(am, bh, acc[nt], 0, 0, 0);
            acc[nt] = __builtin_amdgcn_mfma_f32_16x16x32_bf16(ah, bm, acc[nt], 0, 0, 0);
            acc[nt] = __builtin_amdgcn_mfma_f32_16x16x32_bf16(al, bh, acc[nt], 0, 0, 0);
            acc[nt] = __builtin_amdgcn_mfma_f32_16x16x32_bf16(am, bm, acc[nt], 0, 0, 0);
            acc[nt] = __builtin_amdgcn_mfma_f32_16x16x32_bf16(ah, bl, acc[nt], 0, 0, 0);
        }
        __builtin_amdgcn_s_setprio(0);

        if (more) {   // write next tile into other buffer (no 2nd barrier)
            const int nb = cur ^ 1;
            uint4 Th, Tm, Tl;
            split3_8(xv, Th, Tm, Tl);
            *(uint4*)&Ah[nb][sr][ss * 8] = Th;
            *(uint4*)&Am[nb][sr][ss * 8] = Tm;
            *(uint4*)&Al[nb][sr][ss * 8] = Tl;
            *(uint4*)&Bh[nb][sr][ss * 8] = wa4;
            *(uint4*)&Bm[nb][sr][ss * 8] = wb4;
            *(uint4*)&Bl[nb][sr][ss * 8] = wc4;
        }
    }

    // epilogue: D[g*4+r][l15] per n-tile
    #pragma unroll
    for (int nt = 0; nt < 4; ++nt) {
        const int cc = col0 + nt * 16 + l15;
        const float bc = b1[cc];
        #pragma unroll
        for (int r = 0; r < 4; ++r) {
            const int rr = row0 + 16 * wv + g * 4 + r;
            H1[(size_t)rr * HID + cc] = tanhf(acc[nt][r] + bc);
        }
    }
}

// ============ GEMM2: z0 = H1 @ W2 + b2 ============
__global__ __launch_bounds__(256) void k_gemm2(
    const float* __restrict__ H1, const float* __restrict__ W2,
    const float* __restrict__ b2, float* __restrict__ zbuf)
{
    __shared__ float W2s[HID][DL];
    const int tid = threadIdx.x;
    for (int l = tid; l < HID * DL; l += 256) W2s[l >> 3][l & 7] = W2[l];
    __syncthreads();
    const int row = blockIdx.x * 32 + (tid >> 3);
    const int d = tid & 7;
    float acc = b2[d];
    const float* hr = H1 + (size_t)row * HID;
    for (int k = 0; k < HID; k += 4) {
        float4 hv = *(const float4*)(hr + k);
        acc += hv.x * W2s[k][d] + hv.y * W2s[k+1][d]
             + hv.z * W2s[k+2][d] + hv.w * W2s[k+3][d];
    }
    zbuf[(size_t)row * DL + d] = acc;
}

// ============ PM field (4 steps) + fused partial-reduce + proj h-update ======
// 16 lanes/row (3 centers/lane). Exact IEEE sqrt/divide in the stiff flow.
// Also emits zAg[row][24] shorts (hi|lo|aux) — the lateral's Gram operands,
// computed ONCE per row instead of per (i-block, tile) pair.
template<int S, bool HP>
__global__ __launch_bounds__(256) void k_pm_proj(
    const float* __restrict__ centers, const float* __restrict__ mus,
    const float* __restrict__ projW, const float* __restrict__ projb,
    float* __restrict__ zbuf, float* __restrict__ hB,
    unsigned short* __restrict__ hTb, unsigned short* __restrict__ zAg,
    const float* __restrict__ pAcc, const float* __restrict__ pDen)
{
    __shared__ float4 cs4[NC][2];
    __shared__ float mu_s[NC];
    __shared__ float pW[DL][CH];
    __shared__ float pb[CH];
    const int tid = threadIdx.x;
    for (int l = tid; l < NC * 2; l += 256) cs4[l >> 1][l & 1] = ((const float4*)centers)[l];
    if (tid < NC) mu_s[tid] = mus[tid];
    for (int l = tid; l < DL * CH; l += 256) pW[l >> 6][l & 63] = projW[l];
    if (tid < CH) pb[tid] = projb[tid];
    __syncthreads();

    const int rloc = tid >> 4;
    const int ln   = tid & 15;
    const int row  = blockIdx.x * 16 + rloc;

    float4 cza[3], czb[3];
    float mur[3];
    #pragma unroll
    for (int k = 0; k < 3; ++k) {
        cza[k] = cs4[ln + 16*k][0];
        czb[k] = cs4[ln + 16*k][1];
        mur[k] = mu_s[ln + 16*k];
    }

    float z[8];
    {
        const float4* zp = (const float4*)(zbuf + (size_t)row * DL);
        float4 a = zp[0], b = zp[1];
        z[0]=a.x; z[1]=a.y; z[2]=a.z; z[3]=a.w;
        z[4]=b.x; z[5]=b.y; z[6]=b.z; z[7]=b.w;
    }

    #pragma unroll
    for (int step = 0; step < 4; ++step) {
        float np = 0.f;
        float gp[8] = {0,0,0,0,0,0,0,0};
        #pragma unroll
        for (int k = 0; k < 3; ++k) {
            float d0 = z[0]-cza[k].x, d1 = z[1]-cza[k].y;
            float d2 = z[2]-cza[k].z, d3 = z[3]-cza[k].w;
            float d4 = z[4]-czb[k].x, d5 = z[5]-czb[k].y;
            float d6 = z[6]-czb[k].z, d7 = z[7]-czb[k].w;
            float r2 = 1e-4f;
            r2 = fmaf(d0,d0,r2); r2 = fmaf(d1,d1,r2);
            r2 = fmaf(d2,d2,r2); r2 = fmaf(d3,d3,r2);
            r2 = fmaf(d4,d4,r2); r2 = fmaf(d5,d5,r2);
            r2 = fmaf(d6,d6,r2); r2 = fmaf(d7,d7,r2);
            float r = sqrtf(r2);
            float mr = mur[k] / r;
            np += mr;
            float t = mr / r2;
            gp[0] = fmaf(-t, d0, gp[0]); gp[1] = fmaf(-t, d1, gp[1]);
            gp[2] = fmaf(-t, d2, gp[2]); gp[3] = fmaf(-t, d3, gp[3]);
            gp[4] = fmaf(-t, d4, gp[4]); gp[5] = fmaf(-t, d5, gp[5]);
            gp[6] = fmaf(-t, d6, gp[6]); gp[7] = fmaf(-t, d7, gp[7]);
        }
        #pragma unroll
        for (int m = 1; m < 16; m <<= 1) {
            np += __shfl_xor(np, m);
            #pragma unroll
            for (int d = 0; d < 8; ++d) gp[d] += __shfl_xor(gp[d], m);
        }
        float s = DT_ / (1.f + np);
        #pragma unroll
        for (int d = 0; d < 8; ++d) {
            z[d] = fmaf(s, gp[d], z[d]);
            z[d] = fminf(fmaxf(z[d], -CLAMP_), CLAMP_);
        }
    }

    if (ln < 8) {
        float zout = z[0];
        #pragma unroll
        for (int d = 1; d < 8; ++d) zout = (ln == d) ? z[d] : zout;
        zbuf[(size_t)row * DL + ln] = zout;
    }

    // ---- emit zAg (j-form: [hi8 | lo8 | ch,cl,1,1,0,0,0,0]) ----
    if (ln < 3) {
        float4 a4 = {z[0], z[1], z[2], z[3]};
        float4 b4 = {z[4], z[5], z[6], z[7]};
        uint4 Whi, Wlo; unsigned int Wc;
        z_split(a4, b4, Whi, Wlo, Wc);
        uint4 Wa; Wa.x = Wc; Wa.y = ONE_BF16 | (ONE_BF16 << 16); Wa.z = 0; Wa.w = 0;
        uint4 outv = (ln == 0) ? Whi : ((ln == 1) ? Wlo : Wa);
        *(uint4*)(zAg + (size_t)row * 24 + ln * 8) = outv;
    }

    const int c0 = ln * 4;
    float hin[4];
    if (HP) {
        float den = 1e-6f;
        #pragma unroll
        for (int s = 0; s < S; ++s) den += pDen[s * B_N + row];
        float inv = GAIN_ / den;
        float4 a = {0.f, 0.f, 0.f, 0.f};
        #pragma unroll
        for (int s = 0; s < S; ++s) {
            float4 p = *(const float4*)(pAcc + (size_t)s * B_N * CH
                                        + (size_t)row * CH + c0);
            a.x += p.x; a.y += p.y; a.z += p.z; a.w += p.w;
        }
        float4 hm = *(const float4*)(hB + (size_t)row * CH + c0);
        hin[0] = fmaf(inv, a.x, hm.x);
        hin[1] = fmaf(inv, a.y, hm.y);
        hin[2] = fmaf(inv, a.z, hm.z);
        hin[3] = fmaf(inv, a.w, hm.w);
    } else {
        #pragma unroll
        for (int k = 0; k < 4; ++k) hin[k] = 0.f;
    }
    #pragma unroll
    for (int k = 0; k < 4; ++k) {
        int c = c0 + k;
        float s = pb[c];
        #pragma unroll
        for (int dd = 0; dd < DL; ++dd) s = fmaf(z[dd], pW[dd][c], s);
        hin[k] = 0.9f * hin[k] + 0.1f * tanhf(s);
    }
    float4 o0 = {hin[0], hin[1], hin[2], hin[3]};
    *(float4*)(hB + (size_t)row * CH + c0) = o0;

    {
        const int jl = row & 63;
        const int colp = (jl & 35) | ((jl & 12) << 1) | ((jl & 16) >> 2);
        const size_t tb = (size_t)(row & ~63) + colp;
        #pragma unroll
        for (int k = 0; k < 4; ++k)
            hTb[(size_t)(c0 + k) * B_N + tb] = bf16_1(hin[k]);
    }
}

// ============ lateral EI: Gram-MFMA weights + MFMA K@h ============
// Gram operands read directly from precomputed zAg (L2-resident, prefetched
// one tile ahead) — no zA LDS buffer, no wave-0-only split staging.
template<int S>
__global__ __launch_bounds__(256, 4) void k_lateral(
    const unsigned short* __restrict__ zAg, const unsigned short* __restrict__ hTb,
    float* __restrict__ pAcc, float* __restrict__ pDen)
{
    __shared__ __align__(16) unsigned short hsT[2][CH][72];
    const int tid  = threadIdx.x;
    const int lane = tid & 63;
    const int wv   = tid >> 6;
    const int l15  = lane & 15;
    const int g    = lane >> 4;
    const int rowbase = blockIdx.x * 64;
    const int t0 = (TILES * blockIdx.y) / S;
    const int t1 = (TILES * (blockIdx.y + 1)) / S;
    const int chS = tid >> 2, segS = tid & 3;

    union u4s8 { uint4 u; short8v v; };

    // i-side B-frag straight from zAg; g==3 swaps [ch,cl,1,1] -> [1,1,ch,cl]
    short8v bZ;
    {
        const int bsel = (g == 2) ? 1 : ((g == 3) ? 2 : 0);
        u4s8 b4;
        b4.u = *(const uint4*)(zAg + (size_t)(rowbase + 16 * wv + l15) * 24 + bsel * 8);
        if (g == 3) { unsigned int t_ = b4.u.x; b4.u.x = b4.u.y; b4.u.y = t_; }
        bZ = b4.v;
    }
    const int asel = (g == 1) ? 1 : ((g == 3) ? 2 : 0);

    short8v bones;
    {
        u4s8 uo;
        uo.u.x = uo.u.y = uo.u.z = uo.u.w = ONE_BF16 | (ONE_BF16 << 16);
        bones = uo.v;
    }

    f32x4 acc0 = {0,0,0,0}, acc1 = {0,0,0,0}, acc2 = {0,0,0,0}, acc3 = {0,0,0,0};
    f32x4 acc4 = {0,0,0,0};
    const f32x4 zc = {0,0,0,0};

    uint4 az4[4];
    // ---- prologue: hsT tile t0 + az preload ----
    {
        const int jb = t0 * 64;
        #pragma unroll
        for (int t = 0; t < 4; ++t)
            az4[t] = *(const uint4*)(zAg + (size_t)(jb + t * 16 + l15) * 24 + asel * 8);
        const unsigned short* hs = hTb + (size_t)chS * B_N + jb + segS * 16;
        *(uint4*)(&hsT[0][chS][segS * 16])     = *(const uint4*)(hs);
        *(uint4*)(&hsT[0][chS][segS * 16 + 8]) = *(const uint4*)(hs + 8);
    }

    #pragma unroll 1
    for (int jt = t0; jt < t1; ++jt) {
        const int cur = (jt - t0) & 1;
        const bool more = (jt + 1 < t1);
        uint4 h0n, h1n, azn0, azn1, azn2, azn3;
        if (more) {
            const int jb2 = (jt + 1) * 64;
            const unsigned short* hs = hTb + (size_t)chS * B_N + jb2 + segS * 16;
            h0n = *(const uint4*)(hs);
            h1n = *(const uint4*)(hs + 8);
            azn0 = *(const uint4*)(zAg + (size_t)(jb2 +  0 + l15) * 24 + asel * 8);
            azn1 = *(const uint4*)(zAg + (size_t)(jb2 + 16 + l15) * 24 + asel * 8);
            azn2 = *(const uint4*)(zAg + (size_t)(jb2 + 32 + l15) * 24 + asel * 8);
            azn3 = *(const uint4*)(zAg + (size_t)(jb2 + 48 + l15) * 24 + asel * 8);
        }
        __syncthreads();   // hsT[cur] ready

        f32x4 gac[4];
        __builtin_amdgcn_s_setprio(1);
        #pragma unroll
        for (int t = 0; t < 4; ++t) {
            u4s8 az; az.u = az4[t];
            gac[t] = __builtin_amdgcn_mfma_f32_16x16x32_bf16(az.v, bZ, zc, 0, 0, 0);
        }
        __builtin_amdgcn_s_setprio(0);

        short8v afr[2];
        #pragma unroll
        for (int kb = 0; kb < 2; ++kb) {
            float w8[8];
            #pragma unroll
            for (int m = 0; m < 8; ++m) {
                float out = gac[2 * kb + (m >> 2)][m & 3];
                float e1 = EXP2(out);
                float e2 = e1 * e1;
                float e4 = e2 * e2;
                float e8 = e4 * e4;
                w8[m] = fmaf(0.8f, e8, -e2);
            }
            u4s8 uf;
            uf.u.x = pack_bf16_rhu(w8[0], w8[1]);
            uf.u.y = pack_bf16_rhu(w8[2], w8[3]);
            uf.u.z = pack_bf16_rhu(w8[4], w8[5]);
            uf.u.w = pack_bf16_rhu(w8[6], w8[7]);
            afr[kb] = uf.v;
        }

        __builtin_amdgcn_s_setprio(1);
        #pragma unroll
        for (int kb = 0; kb < 2; ++kb) {
            const int jo = kb * 32 + g * 8;
            short8v b0 = *(const short8v*)&hsT[cur][ 0 + l15][jo];
            short8v b1 = *(const short8v*)&hsT[cur][16 + l15][jo];
            short8v b2 = *(const short8v*)&hsT[cur][32 + l15][jo];
            short8v b3 = *(const short8v*)&hsT[cur][48 + l15][jo];
            acc0 = __builtin_amdgcn_mfma_f32_16x16x32_bf16(afr[kb], b0, acc0, 0, 0, 0);
            acc1 = __builtin_amdgcn_mfma_f32_16x16x32_bf16(afr[kb], b1, acc1, 0, 0, 0);
            acc2 = __builtin_amdgcn_mfma_f32_16x16x32_bf16(afr[kb], b2, acc2, 0, 0, 0);
            acc3 = __builtin_amdgcn_mfma_f32_16x16x32_bf16(afr[kb], b3, acc3, 0, 0, 0);
            acc4 = __builtin_amdgcn_mfma_f32_16x16x32_bf16(afr[kb], bones, acc4, 0, 0, 0);
        }
        __builtin_amdgcn_s_setprio(0);

        if (more) {   // hsT[nb] write (no 2nd barrier: nobody reads nb yet)
            const int nb = cur ^ 1;
            *(uint4*)(&hsT[nb][chS][segS * 16])     = h0n;
            *(uint4*)(&hsT[nb][chS][segS * 16 + 8]) = h1n;
            az4[0] = azn0; az4[1] = azn1; az4[2] = azn2; az4[3] = azn3;
        }
    }

    float* pA = pAcc + (size_t)blockIdx.y * (B_N * CH) + (size_t)rowbase * CH;
    #pragma unroll
    for (int r = 0; r < 4; ++r) {
        int gi = 16 * wv + g * 4 + r;
        pA[(size_t)gi * CH +  0 + l15] = acc0[r];
        pA[(size_t)gi * CH + 16 + l15] = acc1[r];
        pA[(size_t)gi * CH + 32 + l15] = acc2[r];
        pA[(size_t)gi * CH + 48 + l15] = acc3[r];
    }
    if (l15 == 0) {
        #pragma unroll
        for (int r = 0; r < 4; ++r)
            pDen[blockIdx.y * B_N + rowbase + 16 * wv + g * 4 + r] = acc4[r];
    }
}

// ============ final: h = hmid + GAIN*acc/den ; logits = h @ roW + rob ======
template<int S>
__global__ __launch_bounds__(256) void k_logits_h(
    const float* __restrict__ hmid, const float* __restrict__ pAcc,
    const float* __restrict__ pDen, const float* __restrict__ roW,
    const float* __restrict__ rob, float* __restrict__ out_logits,
    float* __restrict__ out_h)
{
    __shared__ float hsh[64][68];
    __shared__ float ro[CH][NCLS];
    __shared__ float rb[NCLS];
    const int tid = threadIdx.x;
    for (int l = tid; l < CH * NCLS; l += 256) ro[l / NCLS][l % NCLS] = roW[l];
    if (tid < NCLS) rb[tid] = rob[tid];
    const int rowbase = blockIdx.x * 64;
    const int r  = tid >> 2;
    const int c0 = (tid & 3) * 16;
    const int row = rowbase + r;
    float den = 1e-6f;
    #pragma unroll
    for (int s = 0; s < S; ++s) den += pDen[s * B_N + row];
    float inv = GAIN_ / den;
    #pragma unroll
    for (int q = 0; q < 4; ++q) {
        float4 a = {0.f, 0.f, 0.f, 0.f};
        #pragma unroll
        for (int s = 0; s < S; ++s) {
            float4 p = *(const float4*)(pAcc + (size_t)s * B_N * CH
                                        + (size_t)row * CH + c0 + q * 4);
            a.x += p.x; a.y += p.y; a.z += p.z; a.w += p.w;
        }
        float4 hm = *(const float4*)(hmid + (size_t)row * CH + c0 + q * 4);
        float4 hv;
        hv.x = fmaf(inv, a.x, hm.x); hv.y = fmaf(inv, a.y, hm.y);
        hv.z = fmaf(inv, a.z, hm.z); hv.w = fmaf(inv, a.w, hm.w);
        *(float4*)(&hsh[r][c0 + q * 4]) = hv;
        *(float4*)(out_h + (size_t)row * CH + c0 + q * 4) = hv;
    }
    __syncthreads();
    for (int idx = tid; idx < 64 * NCLS; idx += 256) {
        int rr = idx / NCLS, o = idx % NCLS;
        float s = rb[o];
        #pragma unroll
        for (int k = 0; k < CH; ++k) s = fmaf(hsh[rr][k], ro[k][o], s);
        out_logits[(size_t)(rowbase + rr) * NCLS + o] = s;
    }
}

// ---- per-split launch helper ----
template<int S>
static void run_all(const float* x, const float* W1, const float* b1,
                    const float* W2, const float* b2, const float* centers,
                    const float* mus, const float* projW, const float* projb,
                    const float* roW, const float* rob,
                    float* ws, float* out, hipStream_t stream)
{
    float* pAcc = ws;
    float* pDen = ws + (size_t)S * B_N * CH;
    float* zbuf = pDen + (size_t)S * B_N;
    float* hB   = zbuf + B_N * DL;
    unsigned short* hTb  = (unsigned short*)(hB + B_N * CH);   // B_N*CH bf16
    unsigned short* zAg  = hTb + (size_t)B_N * CH;             // B_N*24 shorts
    unsigned short* W1aT = zAg + (size_t)B_N * 24;             // 256*800
    unsigned short* W1bT = W1aT + (size_t)HID * KPAD;
    unsigned short* W1cT = W1bT + (size_t)HID * KPAD;
    float* H1   = ws;   // pre-loop only; fits under pAcc (S >= 4)

    float* out_logits = out;
    float* out_z      = out + 81920;
    float* out_h      = out_z + 65536;

    k_w1split<<<KPAD, HID, 0, stream>>>(W1, W1aT, W1bT, W1cT);
    k_gemm1_tanh<<<dim3(B_N / 64, HID / 64), 256, 0, stream>>>(x, W1aT, W1bT, W1cT, b1, H1);
    k_gemm2<<<B_N / 32, 256, 0, stream>>>(H1, W2, b2, zbuf);

    for (int t = 0; t < T_ITERS; ++t) {
        if (t == 0)
            k_pm_proj<S, false><<<B_N / 16, 256, 0, stream>>>(
                centers, mus, projW, projb, zbuf, hB, hTb, zAg, pAcc, pDen);
        else
            k_pm_proj<S, true><<<B_N / 16, 256, 0, stream>>>(
                centers, mus, projW, projb, zbuf, hB, hTb, zAg, pAcc, pDen);
        k_lateral<S><<<dim3(TILES, S), 256, 0, stream>>>(zAg, hTb, pAcc, pDen);
    }

    k_logits_h<S><<<TILES, 256, 0, stream>>>(hB, pAcc, pDen, roW, rob,
                                             out_logits, out_h);
    hipMemcpyAsync(out_z, zbuf, (size_t)B_N * DL * sizeof(float),
                   hipMemcpyDeviceToDevice, stream);
}

extern "C" void kernel_launch(void* const* d_in, const int* in_sizes, int n_in,
                              void* d_out, int out_size, void* d_ws, size_t ws_size,
                              hipStream_t stream)
{
    const float* x       = (const float*)d_in[0];
    const float* W1      = (const float*)d_in[1];
    const float* b1      = (const float*)d_in[2];
    const float* W2      = (const float*)d_in[3];
    const float* b2      = (const float*)d_in[4];
    const float* centers = (const float*)d_in[5];
    const float* mus     = (const float*)d_in[6];
    const float* projW   = (const float*)d_in[7];
    const float* projb   = (const float*)d_in[8];
    const float* roW     = (const float*)d_in[9];
    const float* rob     = (const float*)d_in[10];

    float* ws  = (float*)d_ws;
    float* out = (float*)d_out;

    // floats: S*B_N*CH + S*B_N + B_N*DL + B_N*CH + B_N*CH/2 (hTb)
    //         + B_N*12 (zAg) + 3*HID*KPAD/2 (W1 split)
    const size_t extraW = (size_t)B_N * 12 + (size_t)3 * HID * KPAD / 2;
    const size_t needS8 = ((size_t)8*B_N*CH + 8*B_N + B_N*DL + B_N*CH + B_N*CH/2 + extraW) * 4;
    const size_t needS4 = ((size_t)4*B_N*CH + 4*B_N + B_N*DL + B_N*CH + B_N*CH/2 + extraW) * 4;

    if (ws_size >= needS8)
        run_all<8>(x, W1, b1, W2, b2, centers, mus, projW, projb, roW, rob, ws, out, stream);
    else if (ws_size >= needS4)
        run_all<4>(x, W1, b1, W2, b2, centers, mus, projW, projb, roW, rob, ws, out, stream);
    else
        run_all<2>(x, W1, b1, W2, b2, centers, mus, projW, projb, roW, rob, ws, out, stream);
}

// Round 15
// 267.327 us; speedup vs baseline: 1.0844x; 1.0018x over previous
//
#include <hip/hip_runtime.h>
#include <hip/hip_bf16.h>
#include <hip/hip_cooperative_groups.h>
#include <math.h>

namespace cg = cooperative_groups;

// ---- problem constants (fixed by setup_inputs) ----
#define B_N      8192
#define IN_DIM   784
#define KPAD     800        // 25 k-tiles of 32, zero-padded
#define HID      256
#define DL       8
#define NC       48
#define CH       64
#define NCLS     10
#define T_ITERS  5
#define TILES    128        // B_N / 64

#define DT_      0.12f
#define CLAMP_   3.0f
#define GAIN_    0.06f
// b = log2(e)/(2*sigma_i^2) = 0.50093578 ; sigma_e = sigma_i/2 -> E-exp = 4x I-exp.
#define SQIL2    0.70776814f
#define ONE_BF16 0x3F80u

#if defined(__has_builtin)
#if __has_builtin(__builtin_amdgcn_exp2f)
#define EXP2(x) __builtin_amdgcn_exp2f(x)
#endif
#endif
#ifndef EXP2
#define EXP2(x) exp2f(x)
#endif

typedef __attribute__((ext_vector_type(8))) short short8v;  // 8 bf16 (4 VGPRs)
typedef __attribute__((ext_vector_type(4))) float f32x4;    // MFMA C/D frag

__device__ __forceinline__ unsigned int pack_bf16_rhu(float lo, float hi) {
    unsigned int b0 = __builtin_bit_cast(unsigned int, lo);
    unsigned int b1 = __builtin_bit_cast(unsigned int, hi);
    return ((b0 + 0x8000u) >> 16) | ((b1 + 0x8000u) & 0xFFFF0000u);
}
__device__ __forceinline__ unsigned short bf16_1(float x) {
    return (unsigned short)((__builtin_bit_cast(unsigned int, x) + 0x8000u) >> 16);
}
__device__ __forceinline__ float bf16_to_f(unsigned short h) {
    return __builtin_bit_cast(float, ((unsigned int)h) << 16);
}

// split one z row (scaled) into hi/lo bf16 + c constant pair (lateral path)
__device__ __forceinline__ void z_split(const float4 a, const float4 b,
                                        uint4& Whi, uint4& Wlo, unsigned int& Wc)
{
    float u[8] = {SQIL2*a.x, SQIL2*a.y, SQIL2*a.z, SQIL2*a.w,
                  SQIL2*b.x, SQIL2*b.y, SQIL2*b.z, SQIL2*b.w};
    float sq = 0.f;
    #pragma unroll
    for (int d = 0; d < 8; ++d) sq = fmaf(u[d], u[d], sq);
    float cn = -0.5f * sq;
    unsigned short hi[8]; float lo[8];
    #pragma unroll
    for (int d = 0; d < 8; ++d) {
        hi[d] = bf16_1(u[d]);
        lo[d] = u[d] - bf16_to_f(hi[d]);
    }
    unsigned short ch_ = bf16_1(cn);
    unsigned short cl_ = bf16_1(cn - bf16_to_f(ch_));
    Whi.x = (unsigned int)hi[0] | ((unsigned int)hi[1] << 16);
    Whi.y = (unsigned int)hi[2] | ((unsigned int)hi[3] << 16);
    Whi.z = (unsigned int)hi[4] | ((unsigned int)hi[5] << 16);
    Whi.w = (unsigned int)hi[6] | ((unsigned int)hi[7] << 16);
    Wlo.x = pack_bf16_rhu(lo[0], lo[1]); Wlo.y = pack_bf16_rhu(lo[2], lo[3]);
    Wlo.z = pack_bf16_rhu(lo[4], lo[5]); Wlo.w = pack_bf16_rhu(lo[6], lo[7]);
    Wc = (unsigned int)ch_ | ((unsigned int)cl_ << 16);
}

// 3-term bf16 split of 8 f32 values (24 mantissa bits -> near-exact)
__device__ __forceinline__ void split3_8(const float v[8],
                                         uint4& Th, uint4& Tm, uint4& Tl)
{
    unsigned short h8[8], m8[8], l8[8];
    #pragma unroll
    for (int d = 0; d < 8; ++d) {
        unsigned short h = bf16_1(v[d]);
        float r1 = v[d] - bf16_to_f(h);
        unsigned short m = bf16_1(r1);
        float r2 = r1 - bf16_to_f(m);
        unsigned short l = bf16_1(r2);
        h8[d] = h; m8[d] = m; l8[d] = l;
    }
    Th.x = (unsigned int)h8[0] | ((unsigned int)h8[1] << 16);
    Th.y = (unsigned int)h8[2] | ((unsigned int)h8[3] << 16);
    Th.z = (unsigned int)h8[4] | ((unsigned int)h8[5] << 16);
    Th.w = (unsigned int)h8[6] | ((unsigned int)h8[7] << 16);
    Tm.x = (unsigned int)m8[0] | ((unsigned int)m8[1] << 16);
    Tm.y = (unsigned int)m8[2] | ((unsigned int)m8[3] << 16);
    Tm.z = (unsigned int)m8[4] | ((unsigned int)m8[5] << 16);
    Tm.w = (unsigned int)m8[6] | ((unsigned int)m8[7] << 16);
    Tl.x = (unsigned int)l8[0] | ((unsigned int)l8[1] << 16);
    Tl.y = (unsigned int)l8[2] | ((unsigned int)l8[3] << 16);
    Tl.z = (unsigned int)l8[4] | ((unsigned int)l8[5] << 16);
    Tl.w = (unsigned int)l8[6] | ((unsigned int)l8[7] << 16);
}

// ============ one-time: W1 -> transposed 3-term bf16, k padded to 800 ========
__global__ __launch_bounds__(256) void k_w1split(
    const float* __restrict__ W1, unsigned short* __restrict__ W1aT,
    unsigned short* __restrict__ W1bT, unsigned short* __restrict__ W1cT)
{
    const int k = blockIdx.x;        // 0..799
    const int n = threadIdx.x;       // 0..255
    float v = (k < IN_DIM) ? W1[(size_t)k * HID + n] : 0.f;
    unsigned short h = bf16_1(v);
    float r1 = v - bf16_to_f(h);
    unsigned short m = bf16_1(r1);
    unsigned short l = bf16_1(r1 - bf16_to_f(m));
    W1aT[(size_t)n * KPAD + k] = h;
    W1bT[(size_t)n * KPAD + k] = m;
    W1cT[(size_t)n * KPAD + k] = l;
}

// ============ encoder GEMM1 via MFMA (3-term bf16 split, f32 accum) ==========
__global__ __launch_bounds__(256, 2) void k_gemm1_tanh(
    const float* __restrict__ x, const unsigned short* __restrict__ W1aT,
    const unsigned short* __restrict__ W1bT, const unsigned short* __restrict__ W1cT,
    const float* __restrict__ b1, float* __restrict__ H1)
{
    __shared__ __align__(16) unsigned short Ah[2][64][40], Am[2][64][40], Al[2][64][40];
    __shared__ __align__(16) unsigned short Bh[2][64][40], Bm[2][64][40], Bl[2][64][40];
    const int tid = threadIdx.x;
    const int row0 = blockIdx.x * 64;
    const int col0 = blockIdx.y * 64;
    const int wv = tid >> 6, lane = tid & 63;
    const int l15 = lane & 15, g = lane >> 4;
    const int sr = tid >> 2, ss = tid & 3;

    f32x4 acc[4] = {{0,0,0,0},{0,0,0,0},{0,0,0,0},{0,0,0,0}};

    {
        float xv[8];
        {
            const float* xp = x + (size_t)(row0 + sr) * IN_DIM + ss * 8;
            float4 a = *(const float4*)(xp), b = *(const float4*)(xp + 4);
            xv[0]=a.x; xv[1]=a.y; xv[2]=a.z; xv[3]=a.w;
            xv[4]=b.x; xv[5]=b.y; xv[6]=b.z; xv[7]=b.w;
        }
        uint4 Th, Tm, Tl;
        split3_8(xv, Th, Tm, Tl);
        *(uint4*)&Ah[0][sr][ss * 8] = Th;
        *(uint4*)&Am[0][sr][ss * 8] = Tm;
        *(uint4*)&Al[0][sr][ss * 8] = Tl;
        const size_t wo = (size_t)(col0 + sr) * KPAD + ss * 8;
        *(uint4*)&Bh[0][sr][ss * 8] = *(const uint4*)(W1aT + wo);
        *(uint4*)&Bm[0][sr][ss * 8] = *(const uint4*)(W1bT + wo);
        *(uint4*)&Bl[0][sr][ss * 8] = *(const uint4*)(W1cT + wo);
    }

    const int NK = KPAD / 32;   // 25
    #pragma unroll 1
    for (int ks = 0; ks < NK; ++ks) {
        const int cur = ks & 1;
        const bool more = (ks + 1 < NK);
        float xv[8];
        uint4 wa4, wb4, wc4;
        if (more) {
            const int k0 = (ks + 1) * 32;
            if (k0 + ss * 8 < IN_DIM) {
                const float* xp = x + (size_t)(row0 + sr) * IN_DIM + k0 + ss * 8;
                float4 a = *(const float4*)(xp), b = *(const float4*)(xp + 4);
                xv[0]=a.x; xv[1]=a.y; xv[2]=a.z; xv[3]=a.w;
                xv[4]=b.x; xv[5]=b.y; xv[6]=b.z; xv[7]=b.w;
            } else {
                #pragma unroll
                for (int d = 0; d < 8; ++d) xv[d] = 0.f;
            }
            const size_t wo = (size_t)(col0 + sr) * KPAD + k0 + ss * 8;
            wa4 = *(const uint4*)(W1aT + wo);
            wb4 = *(const uint4*)(W1bT + wo);
            wc4 = *(const uint4*)(W1cT + wo);
        }
        __syncthreads();

        short8v ah = *(const short8v*)&Ah[cur][16 * wv + l15][g * 8];
        short8v am = *(const short8v*)&Am[cur][16 * wv + l15][g * 8];
        short8v al = *(const short8v*)&Al[cur][16 * wv + l15][g * 8];
        __builtin_amdgcn_s_setprio(1);
        #pragma unroll
        for (int nt = 0; nt < 4; ++nt) {
            short8v bh = *(const short8v*)&Bh[cur][nt * 16 + l15][g * 8];
            short8v bm = *(const short8v*)&Bm[cur][nt * 16 + l15][g * 8];
            short8v bl = *(const short8v*)&Bl[cur][nt * 16 + l15][g * 8];
            acc[nt] = __builtin_amdgcn_mfma_f32_16x16x32_bf16(ah, bh, acc[nt], 0, 0, 0);
            acc[nt] = __builtin_amdgcn_mfma_f32_16x16x32_bf16(am, bh, acc[nt], 0, 0, 0);
            acc[nt] = __builtin_amdgcn_mfma_f32_16x16x32_bf16(ah, bm, acc[nt], 0, 0, 0);
            acc[nt] = __builtin_amdgcn_mfma_f32_16x16x32_bf16(al, bh, acc[nt], 0, 0, 0);
            acc[nt] = __builtin_amdgcn_mfma_f32_16x16x32_bf16(am, bm, acc[nt], 0, 0, 0);
            acc[nt] = __builtin_amdgcn_mfma_f32_16x16x32_bf16(ah, bl, acc[nt], 0, 0, 0);
        }
        __builtin_amdgcn_s_setprio(0);

        if (more) {
            const int nb = cur ^ 1;
            uint4 Th, Tm, Tl;
            split3_8(xv, Th, Tm, Tl);
            *(uint4*)&Ah[nb][sr][ss * 8] = Th;
            *(uint4*)&Am[nb][sr][ss * 8] = Tm;
            *(uint4*)&Al[nb][sr][ss * 8] = Tl;
            *(uint4*)&Bh[nb][sr][ss * 8] = wa4;
            *(uint4*)&Bm[nb][sr][ss * 8] = wb4;
            *(uint4*)&Bl[nb][sr][ss * 8] = wc4;
        }
    }

    #pragma unroll
    for (int nt = 0; nt < 4; ++nt) {
        const int cc = col0 + nt * 16 + l15;
        const float bc = b1[cc];
        #pragma unroll
        for (int r = 0; r < 4; ++r) {
            const int rr = row0 + 16 * wv + g * 4 + r;
            H1[(size_t)rr * HID + cc] = tanhf(acc[nt][r] + bc);
        }
    }
}

// ============ GEMM2: z0 = H1 @ W2 + b2 (separate-kernel path) ============
__global__ __launch_bounds__(256) void k_gemm2(
    const float* __restrict__ H1, const float* __restrict__ W2,
    const float* __restrict__ b2, float* __restrict__ zbuf)
{
    __shared__ float W2s[HID][DL];
    const int tid = threadIdx.x;
    for (int l = tid; l < HID * DL; l += 256) W2s[l >> 3][l & 7] = W2[l];
    __syncthreads();
    const int row = blockIdx.x * 32 + (tid >> 3);
    const int d = tid & 7;
    float acc = b2[d];
    const float* hr = H1 + (size_t)row * HID;
    for (int k = 0; k < HID; k += 4) {
        float4 hv = *(const float4*)(hr + k);
        acc += hv.x * W2s[k][d] + hv.y * W2s[k+1][d]
             + hv.z * W2s[k+2][d] + hv.w * W2s[k+3][d];
    }
    zbuf[(size_t)row * DL + d] = acc;
}

// ===== shared phase bodies (used verbatim by both paths) =====
template<int S>
__device__ __forceinline__ void pm_body(
    int bid, int tid, bool hp,
    const float4 (*cs4)[2], const float* mu_s,
    const float (*pW)[CH], const float* pb,
    float* zbuf, float* hB, unsigned short* hTb,
    unsigned short* zAg, const float* pAcc, const float* pDen)
{
    const int rloc = tid >> 4;
    const int ln   = tid & 15;
    const int row  = bid * 16 + rloc;

    float4 cza[3], czb[3];
    float mur[3];
    #pragma unroll
    for (int k = 0; k < 3; ++k) {
        cza[k] = cs4[ln + 16*k][0];
        czb[k] = cs4[ln + 16*k][1];
        mur[k] = mu_s[ln + 16*k];
    }

    float z[8];
    {
        const float4* zp = (const float4*)(zbuf + (size_t)row * DL);
        float4 a = zp[0], b = zp[1];
        z[0]=a.x; z[1]=a.y; z[2]=a.z; z[3]=a.w;
        z[4]=b.x; z[5]=b.y; z[6]=b.z; z[7]=b.w;
    }

    #pragma unroll
    for (int step = 0; step < 4; ++step) {
        float np = 0.f;
        float gp[8] = {0,0,0,0,0,0,0,0};
        #pragma unroll
        for (int k = 0; k < 3; ++k) {
            float d0 = z[0]-cza[k].x, d1 = z[1]-cza[k].y;
            float d2 = z[2]-cza[k].z, d3 = z[3]-cza[k].w;
            float d4 = z[4]-czb[k].x, d5 = z[5]-czb[k].y;
            float d6 = z[6]-czb[k].z, d7 = z[7]-czb[k].w;
            float r2 = 1e-4f;
            r2 = fmaf(d0,d0,r2); r2 = fmaf(d1,d1,r2);
            r2 = fmaf(d2,d2,r2); r2 = fmaf(d3,d3,r2);
            r2 = fmaf(d4,d4,r2); r2 = fmaf(d5,d5,r2);
            r2 = fmaf(d6,d6,r2); r2 = fmaf(d7,d7,r2);
            float r = sqrtf(r2);
            float mr = mur[k] / r;
            np += mr;
            float tt = mr / r2;
            gp[0] = fmaf(-tt, d0, gp[0]); gp[1] = fmaf(-tt, d1, gp[1]);
            gp[2] = fmaf(-tt, d2, gp[2]); gp[3] = fmaf(-tt, d3, gp[3]);
            gp[4] = fmaf(-tt, d4, gp[4]); gp[5] = fmaf(-tt, d5, gp[5]);
            gp[6] = fmaf(-tt, d6, gp[6]); gp[7] = fmaf(-tt, d7, gp[7]);
        }
        #pragma unroll
        for (int m = 1; m < 16; m <<= 1) {
            np += __shfl_xor(np, m);
            #pragma unroll
            for (int d = 0; d < 8; ++d) gp[d] += __shfl_xor(gp[d], m);
        }
        float s = DT_ / (1.f + np);
        #pragma unroll
        for (int d = 0; d < 8; ++d) {
            z[d] = fmaf(s, gp[d], z[d]);
            z[d] = fminf(fmaxf(z[d], -CLAMP_), CLAMP_);
        }
    }

    if (ln < 8) {
        float zout = z[0];
        #pragma unroll
        for (int d = 1; d < 8; ++d) zout = (ln == d) ? z[d] : zout;
        zbuf[(size_t)row * DL + ln] = zout;
    }

    if (ln < 3) {
        float4 a4 = {z[0], z[1], z[2], z[3]};
        float4 b4 = {z[4], z[5], z[6], z[7]};
        uint4 Whi, Wlo; unsigned int Wc;
        z_split(a4, b4, Whi, Wlo, Wc);
        uint4 Wa; Wa.x = Wc; Wa.y = ONE_BF16 | (ONE_BF16 << 16); Wa.z = 0; Wa.w = 0;
        uint4 outv = (ln == 0) ? Whi : ((ln == 1) ? Wlo : Wa);
        *(uint4*)(zAg + (size_t)row * 24 + ln * 8) = outv;
    }

    const int c0 = ln * 4;
    float hin[4];
    if (hp) {
        float den = 1e-6f;
        #pragma unroll
        for (int s = 0; s < S; ++s) den += pDen[s * B_N + row];
        float inv = GAIN_ / den;
        float4 a = {0.f, 0.f, 0.f, 0.f};
        #pragma unroll
        for (int s = 0; s < S; ++s) {
            float4 p = *(const float4*)(pAcc + (size_t)s * B_N * CH
                                        + (size_t)row * CH + c0);
            a.x += p.x; a.y += p.y; a.z += p.z; a.w += p.w;
        }
        float4 hm = *(const float4*)(hB + (size_t)row * CH + c0);
        hin[0] = fmaf(inv, a.x, hm.x);
        hin[1] = fmaf(inv, a.y, hm.y);
        hin[2] = fmaf(inv, a.z, hm.z);
        hin[3] = fmaf(inv, a.w, hm.w);
    } else {
        #pragma unroll
        for (int k = 0; k < 4; ++k) hin[k] = 0.f;
    }
    #pragma unroll
    for (int k = 0; k < 4; ++k) {
        int c = c0 + k;
        float s = pb[c];
        #pragma unroll
        for (int dd = 0; dd < DL; ++dd) s = fmaf(z[dd], pW[dd][c], s);
        hin[k] = 0.9f * hin[k] + 0.1f * tanhf(s);
    }
    float4 o0 = {hin[0], hin[1], hin[2], hin[3]};
    *(float4*)(hB + (size_t)row * CH + c0) = o0;

    {
        const int jl = row & 63;
        const int colp = (jl & 35) | ((jl & 12) << 1) | ((jl & 16) >> 2);
        const size_t tb = (size_t)(row & ~63) + colp;
        #pragma unroll
        for (int k = 0; k < 4; ++k)
            hTb[(size_t)(c0 + k) * B_N + tb] = bf16_1(hin[k]);
    }
}

template<int S>
__device__ __forceinline__ void lat_body(
    int ib, int sp, int tid, unsigned short (*hsT)[CH][72],
    const unsigned short* zAg, const unsigned short* hTb,
    float* pAcc, float* pDen)
{
    const int lane = tid & 63;
    const int wv   = tid >> 6;
    const int l15  = lane & 15;
    const int g    = lane >> 4;
    const int rowbase = ib * 64;
    const int t0 = (TILES * sp) / S;
    const int t1 = (TILES * (sp + 1)) / S;
    const int chS = tid >> 2, segS = tid & 3;

    union u4s8 { uint4 u; short8v v; };

    short8v bZ;
    {
        const int bsel = (g == 2) ? 1 : ((g == 3) ? 2 : 0);
        u4s8 b4;
        b4.u = *(const uint4*)(zAg + (size_t)(rowbase + 16 * wv + l15) * 24 + bsel * 8);
        if (g == 3) { unsigned int t_ = b4.u.x; b4.u.x = b4.u.y; b4.u.y = t_; }
        bZ = b4.v;
    }
    const int asel = (g == 1) ? 1 : ((g == 3) ? 2 : 0);

    short8v bones;
    {
        u4s8 uo;
        uo.u.x = uo.u.y = uo.u.z = uo.u.w = ONE_BF16 | (ONE_BF16 << 16);
        bones = uo.v;
    }

    f32x4 acc0 = {0,0,0,0}, acc1 = {0,0,0,0}, acc2 = {0,0,0,0}, acc3 = {0,0,0,0};
    f32x4 acc4 = {0,0,0,0};
    const f32x4 zc = {0,0,0,0};

    uint4 az4[4];
    {
        const int jb = t0 * 64;
        #pragma unroll
        for (int tt = 0; tt < 4; ++tt)
            az4[tt] = *(const uint4*)(zAg + (size_t)(jb + tt * 16 + l15) * 24 + asel * 8);
        const unsigned short* hs = hTb + (size_t)chS * B_N + jb + segS * 16;
        *(uint4*)(&hsT[0][chS][segS * 16])     = *(const uint4*)(hs);
        *(uint4*)(&hsT[0][chS][segS * 16 + 8]) = *(const uint4*)(hs + 8);
    }

    #pragma unroll 1
    for (int jt = t0; jt < t1; ++jt) {
        const int cur = (jt - t0) & 1;
        const bool more = (jt + 1 < t1);
        uint4 h0n, h1n, azn0, azn1, azn2, azn3;
        if (more) {
            const int jb2 = (jt + 1) * 64;
            const unsigned short* hs = hTb + (size_t)chS * B_N + jb2 + segS * 16;
            h0n = *(const uint4*)(hs);
            h1n = *(const uint4*)(hs + 8);
            azn0 = *(const uint4*)(zAg + (size_t)(jb2 +  0 + l15) * 24 + asel * 8);
            azn1 = *(const uint4*)(zAg + (size_t)(jb2 + 16 + l15) * 24 + asel * 8);
            azn2 = *(const uint4*)(zAg + (size_t)(jb2 + 32 + l15) * 24 + asel * 8);
            azn3 = *(const uint4*)(zAg + (size_t)(jb2 + 48 + l15) * 24 + asel * 8);
        }
        __syncthreads();   // hsT[cur] ready

        f32x4 gac[4];
        __builtin_amdgcn_s_setprio(1);
        #pragma unroll
        for (int tt = 0; tt < 4; ++tt) {
            u4s8 az; az.u = az4[tt];
            gac[tt] = __builtin_amdgcn_mfma_f32_16x16x32_bf16(az.v, bZ, zc, 0, 0, 0);
        }
        __builtin_amdgcn_s_setprio(0);

        short8v afr[2];
        #pragma unroll
        for (int kb = 0; kb < 2; ++kb) {
            float w8[8];
            #pragma unroll
            for (int m = 0; m < 8; ++m) {
                float out = gac[2 * kb + (m >> 2)][m & 3];
                float e1 = EXP2(out);
                float e2 = e1 * e1;
                float e4 = e2 * e2;
                float e8 = e4 * e4;
                w8[m] = fmaf(0.8f, e8, -e2);
            }
            u4s8 uf;
            uf.u.x = pack_bf16_rhu(w8[0], w8[1]);
            uf.u.y = pack_bf16_rhu(w8[2], w8[3]);
            uf.u.z = pack_bf16_rhu(w8[4], w8[5]);
            uf.u.w = pack_bf16_rhu(w8[6], w8[7]);
            afr[kb] = uf.v;
        }

        __builtin_amdgcn_s_setprio(1);
        #pragma unroll
        for (int kb = 0; kb < 2; ++kb) {
            const int jo = kb * 32 + g * 8;
            short8v b0 = *(const short8v*)&hsT[cur][ 0 + l15][jo];
            short8v b1 = *(const short8v*)&hsT[cur][16 + l15][jo];
            short8v b2 = *(const short8v*)&hsT[cur][32 + l15][jo];
            short8v b3 = *(const short8v*)&hsT[cur][48 + l15][jo];
            acc0 = __builtin_amdgcn_mfma_f32_16x16x32_bf16(afr[kb], b0, acc0, 0, 0, 0);
            acc1 = __builtin_amdgcn_mfma_f32_16x16x32_bf16(afr[kb], b1, acc1, 0, 0, 0);
            acc2 = __builtin_amdgcn_mfma_f32_16x16x32_bf16(afr[kb], b2, acc2, 0, 0, 0);
            acc3 = __builtin_amdgcn_mfma_f32_16x16x32_bf16(afr[kb], b3, acc3, 0, 0, 0);
            acc4 = __builtin_amdgcn_mfma_f32_16x16x32_bf16(afr[kb], bones, acc4, 0, 0, 0);
        }
        __builtin_amdgcn_s_setprio(0);

        if (more) {
            const int nb = cur ^ 1;
            *(uint4*)(&hsT[nb][chS][segS * 16])     = h0n;
            *(uint4*)(&hsT[nb][chS][segS * 16 + 8]) = h1n;
            az4[0] = azn0; az4[1] = azn1; az4[2] = azn2; az4[3] = azn3;
        }
    }

    float* pA = pAcc + (size_t)sp * (B_N * CH) + (size_t)rowbase * CH;
    #pragma unroll
    for (int r = 0; r < 4; ++r) {
        int gi = 16 * wv + g * 4 + r;
        pA[(size_t)gi * CH +  0 + l15] = acc0[r];
        pA[(size_t)gi * CH + 16 + l15] = acc1[r];
        pA[(size_t)gi * CH + 32 + l15] = acc2[r];
        pA[(size_t)gi * CH + 48 + l15] = acc3[r];
    }
    if (l15 == 0) {
        #pragma unroll
        for (int r = 0; r < 4; ++r)
            pDen[sp * B_N + rowbase + 16 * wv + g * 4 + r] = acc4[r];
    }
}

// ============ separate-kernel path (round-13, known good) ============
template<int S, bool HP>
__global__ __launch_bounds__(256) void k_pm_proj(
    const float* __restrict__ centers, const float* __restrict__ mus,
    const float* __restrict__ projW, const float* __restrict__ projb,
    float* __restrict__ zbuf, float* __restrict__ hB,
    unsigned short* __restrict__ hTb, unsigned short* __restrict__ zAg,
    const float* __restrict__ pAcc, const float* __restrict__ pDen)
{
    __shared__ float4 cs4[NC][2];
    __shared__ float mu_s[NC];
    __shared__ float pW[DL][CH];
    __shared__ float pb[CH];
    const int tid = threadIdx.x;
    for (int l = tid; l < NC * 2; l += 256) cs4[l >> 1][l & 1] = ((const float4*)centers)[l];
    if (tid < NC) mu_s[tid] = mus[tid];
    for (int l = tid; l < DL * CH; l += 256) pW[l >> 6][l & 63] = projW[l];
    if (tid < CH) pb[tid] = projb[tid];
    __syncthreads();
    pm_body<S>(blockIdx.x, tid, HP, cs4, mu_s, pW, pb, zbuf, hB, hTb, zAg, pAcc, pDen);
}

template<int S>
__global__ __launch_bounds__(256, 4) void k_lateral(
    const unsigned short* __restrict__ zAg, const unsigned short* __restrict__ hTb,
    float* __restrict__ pAcc, float* __restrict__ pDen)
{
    __shared__ __align__(16) unsigned short hsT[2][CH][72];
    lat_body<S>(blockIdx.x, blockIdx.y, threadIdx.x, hsT, zAg, hTb, pAcc, pDen);
}

template<int S>
__global__ __launch_bounds__(256) void k_logits_h(
    const float* __restrict__ hmid, const float* __restrict__ pAcc,
    const float* __restrict__ pDen, const float* __restrict__ roW,
    const float* __restrict__ rob, float* __restrict__ out_logits,
    float* __restrict__ out_h)
{
    __shared__ float hsh[64][68];
    __shared__ float ro[CH][NCLS];
    __shared__ float rb[NCLS];
    const int tid = threadIdx.x;
    for (int l = tid; l < CH * NCLS; l += 256) ro[l / NCLS][l % NCLS] = roW[l];
    if (tid < NCLS) rb[tid] = rob[tid];
    const int rowbase = blockIdx.x * 64;
    const int r  = tid >> 2;
    const int c0 = (tid & 3) * 16;
    const int row = rowbase + r;
    float den = 1e-6f;
    #pragma unroll
    for (int s = 0; s < S; ++s) den += pDen[s * B_N + row];
    float inv = GAIN_ / den;
    #pragma unroll
    for (int q = 0; q < 4; ++q) {
        float4 a = {0.f, 0.f, 0.f, 0.f};
        #pragma unroll
        for (int s = 0; s < S; ++s) {
            float4 p = *(const float4*)(pAcc + (size_t)s * B_N * CH
                                        + (size_t)row * CH + c0 + q * 4);
            a.x += p.x; a.y += p.y; a.z += p.z; a.w += p.w;
        }
        float4 hm = *(const float4*)(hmid + (size_t)row * CH + c0 + q * 4);
        float4 hv;
        hv.x = fmaf(inv, a.x, hm.x); hv.y = fmaf(inv, a.y, hm.y);
        hv.z = fmaf(inv, a.z, hm.z); hv.w = fmaf(inv, a.w, hm.w);
        *(float4*)(&hsh[r][c0 + q * 4]) = hv;
        *(float4*)(out_h + (size_t)row * CH + c0 + q * 4) = hv;
    }
    __syncthreads();
    for (int idx = tid; idx < 64 * NCLS; idx += 256) {
        int rr = idx / NCLS, o = idx % NCLS;
        float s = rb[o];
        #pragma unroll
        for (int k = 0; k < CH; ++k) s = fmaf(hsh[rr][k], ro[k][o], s);
        out_logits[(size_t)(rowbase + rr) * NCLS + o] = s;
    }
}

// ============ fused cooperative kernel (gated) ============
template<int S>
__global__ __launch_bounds__(256, 4) void k_fused(
    const float* H1, const float* W2, const float* b2,
    const float* centers, const float* mus,
    const float* projW, const float* projb,
    const float* roW, const float* rob,
    float* zbuf, float* hB,
    unsigned short* hTb, unsigned short* zAg,
    float* pAcc, float* pDen,
    float* out_logits, float* out_h)
{
    cg::grid_group grid = cg::this_grid();
    const int bid = blockIdx.x;
    const int tid = threadIdx.x;

    __shared__ float4 cs4[NC][2];
    __shared__ float mu_s[NC];
    __shared__ float pW[DL][CH];
    __shared__ float pb[CH];
    __shared__ union __align__(16) {
        unsigned short hsT[2][CH][72];
        struct { float hsh[64][68]; float ro[CH][NCLS]; float rb[NCLS]; } lg;
        float W2s[HID][DL];
    } su;

    for (int l = tid; l < NC * 2; l += 256) cs4[l >> 1][l & 1] = ((const float4*)centers)[l];
    if (tid < NC) mu_s[tid] = mus[tid];
    for (int l = tid; l < DL * CH; l += 256) pW[l >> 6][l & 63] = projW[l];
    if (tid < CH) pb[tid] = projb[tid];

    // G2
    if (bid < 256) {
        for (int l = tid; l < HID * DL; l += 256) su.W2s[l >> 3][l & 7] = W2[l];
        __syncthreads();
        const int row = bid * 32 + (tid >> 3);
        const int d = tid & 7;
        float acc = b2[d];
        const float* hr = H1 + (size_t)row * HID;
        for (int k = 0; k < HID; k += 4) {
            float4 hv = *(const float4*)(hr + k);
            acc += hv.x * su.W2s[k][d] + hv.y * su.W2s[k+1][d]
                 + hv.z * su.W2s[k+2][d] + hv.w * su.W2s[k+3][d];
        }
        zbuf[(size_t)row * DL + d] = acc;
    }
    grid.sync();

    #pragma unroll 1
    for (int t = 0; t < T_ITERS; ++t) {
        if (bid < 512)
            pm_body<S>(bid, tid, t > 0, cs4, mu_s, pW, pb, zbuf, hB, hTb, zAg, pAcc, pDen);
        grid.sync();
        lat_body<S>(bid & (TILES - 1), bid >> 7, tid, su.hsT, zAg, hTb, pAcc, pDen);
        grid.sync();
    }

    if (bid < 128) {
        const int rowbase = bid * 64;
        for (int l = tid; l < CH * NCLS; l += 256) su.lg.ro[l / NCLS][l % NCLS] = roW[l];
        if (tid < NCLS) su.lg.rb[tid] = rob[tid];
        const int r  = tid >> 2;
        const int c0 = (tid & 3) * 16;
        const int row = rowbase + r;
        float den = 1e-6f;
        #pragma unroll
        for (int s = 0; s < S; ++s) den += pDen[s * B_N + row];
        float inv = GAIN_ / den;
        #pragma unroll
        for (int q = 0; q < 4; ++q) {
            float4 a = {0.f, 0.f, 0.f, 0.f};
            #pragma unroll
            for (int s = 0; s < S; ++s) {
                float4 p = *(const float4*)(pAcc + (size_t)s * B_N * CH
                                            + (size_t)row * CH + c0 + q * 4);
                a.x += p.x; a.y += p.y; a.z += p.z; a.w += p.w;
            }
            float4 hm = *(const float4*)(hB + (size_t)row * CH + c0 + q * 4);
            float4 hv;
            hv.x = fmaf(inv, a.x, hm.x); hv.y = fmaf(inv, a.y, hm.y);
            hv.z = fmaf(inv, a.z, hm.z); hv.w = fmaf(inv, a.w, hm.w);
            *(float4*)(&su.lg.hsh[r][c0 + q * 4]) = hv;
            *(float4*)(out_h + (size_t)row * CH + c0 + q * 4) = hv;
        }
        __syncthreads();
        for (int idx = tid; idx < 64 * NCLS; idx += 256) {
            int rr = idx / NCLS, o = idx % NCLS;
            float s = su.lg.rb[o];
            #pragma unroll
            for (int k = 0; k < CH; ++k) s = fmaf(su.lg.hsh[rr][k], su.lg.ro[k][o], s);
            out_logits[(size_t)(rowbase + rr) * NCLS + o] = s;
        }
    }
}

// ---- per-split launch helper ----
template<int S>
static void run_all(const float* x, const float* W1, const float* b1,
                    const float* W2, const float* b2, const float* centers,
                    const float* mus, const float* projW, const float* projb,
                    const float* roW, const float* rob,
                    float* ws, float* out, hipStream_t stream)
{
    float* pAcc = ws;
    float* pDen = ws + (size_t)S * B_N * CH;
    float* zbuf = pDen + (size_t)S * B_N;
    float* hB   = zbuf + B_N * DL;
    unsigned short* hTb  = (unsigned short*)(hB + B_N * CH);
    unsigned short* zAg  = hTb + (size_t)B_N * CH;
    unsigned short* W1aT = zAg + (size_t)B_N * 24;
    unsigned short* W1bT = W1aT + (size_t)HID * KPAD;
    unsigned short* W1cT = W1bT + (size_t)HID * KPAD;
    float* H1 = (float*)(W1cT + (size_t)HID * KPAD);

    float* out_logits = out;
    float* out_z      = out + 81920;
    float* out_h      = out_z + 65536;

    k_w1split<<<KPAD, HID, 0, stream>>>(W1, W1aT, W1bT, W1cT);
    k_gemm1_tanh<<<dim3(B_N / 64, HID / 64), 256, 0, stream>>>(x, W1aT, W1bT, W1cT, b1, H1);

    // gate the cooperative path on host-side capability queries (deterministic,
    // graph-capture-safe: no stream ops). Fall back to round-13 kernels.
    bool coop = false;
    {
        int dev = 0;
        if (hipGetDevice(&dev) == hipSuccess) {
            int attr = 0, ncu = 0, nb = 0;
            hipDeviceGetAttribute(&attr, hipDeviceAttributeCooperativeLaunch, dev);
            hipDeviceGetAttribute(&ncu, hipDeviceAttributeMultiprocessorCount, dev);
            hipError_t q = hipOccupancyMaxActiveBlocksPerMultiprocessor(
                &nb, k_fused<S>, 256, 0);
            coop = (attr != 0) && (q == hipSuccess) && ((size_t)nb * ncu >= TILES * S);
        }
    }

    if (coop) {
        const float* H1c = H1;
        void* kargs[] = {
            (void*)&H1c, (void*)&W2, (void*)&b2, (void*)&centers, (void*)&mus,
            (void*)&projW, (void*)&projb, (void*)&roW, (void*)&rob,
            (void*)&zbuf, (void*)&hB, (void*)&hTb, (void*)&zAg,
            (void*)&pAcc, (void*)&pDen, (void*)&out_logits, (void*)&out_h };
        hipError_t lerr = hipLaunchCooperativeKernel(
            reinterpret_cast<void*>(&k_fused<S>), dim3(TILES * S), dim3(256),
            kargs, 0, stream);
        if (lerr != hipSuccess) coop = false;
    }

    if (!coop) {
        k_gemm2<<<B_N / 32, 256, 0, stream>>>(H1, W2, b2, zbuf);
        for (int t = 0; t < T_ITERS; ++t) {
            if (t == 0)
                k_pm_proj<S, false><<<B_N / 16, 256, 0, stream>>>(
                    centers, mus, projW, projb, zbuf, hB, hTb, zAg, pAcc, pDen);
            else
                k_pm_proj<S, true><<<B_N / 16, 256, 0, stream>>>(
                    centers, mus, projW, projb, zbuf, hB, hTb, zAg, pAcc, pDen);
            k_lateral<S><<<dim3(TILES, S), 256, 0, stream>>>(zAg, hTb, pAcc, pDen);
        }
        k_logits_h<S><<<TILES, 256, 0, stream>>>(hB, pAcc, pDen, roW, rob,
                                                 out_logits, out_h);
    }

    hipMemcpyAsync(out_z, zbuf, (size_t)B_N * DL * sizeof(float),
                   hipMemcpyDeviceToDevice, stream);
}

extern "C" void kernel_launch(void* const* d_in, const int* in_sizes, int n_in,
                              void* d_out, int out_size, void* d_ws, size_t ws_size,
                              hipStream_t stream)
{
    const float* x       = (const float*)d_in[0];
    const float* W1      = (const float*)d_in[1];
    const float* b1      = (const float*)d_in[2];
    const float* W2      = (const float*)d_in[3];
    const float* b2      = (const float*)d_in[4];
    const float* centers = (const float*)d_in[5];
    const float* mus     = (const float*)d_in[6];
    const float* projW   = (const float*)d_in[7];
    const float* projb   = (const float*)d_in[8];
    const float* roW     = (const float*)d_in[9];
    const float* rob     = (const float*)d_in[10];

    float* ws  = (float*)d_ws;
    float* out = (float*)d_out;

    const size_t extraW = (size_t)B_N * 12 + (size_t)3 * HID * KPAD / 2 + (size_t)B_N * HID;
    const size_t needS8 = ((size_t)8*B_N*CH + 8*B_N + B_N*DL + B_N*CH + B_N*CH/2 + extraW) * 4;
    const size_t needS4 = ((size_t)4*B_N*CH + 4*B_N + B_N*DL + B_N*CH + B_N*CH/2 + extraW) * 4;

    if (ws_size >= needS8)
        run_all<8>(x, W1, b1, W2, b2, centers, mus, projW, projb, roW, rob, ws, out, stream);
    else if (ws_size >= needS4)
        run_all<4>(x, W1, b1, W2, b2, centers, mus, projW, projb, roW, rob, ws, out, stream);
    else
        run_all<2>(x, W1, b1, W2, b2, centers, mus, projW, projb, roW, rob, ws, out, stream);
}

// Round 16
// 265.057 us; speedup vs baseline: 1.0937x; 1.0086x over previous
//
#include <hip/hip_runtime.h>
#include <hip/hip_bf16.h>
#include <math.h>

// ---- problem constants (fixed by setup_inputs) ----
#define B_N      8192
#define IN_DIM   784
#define KPAD     800        // 25 k-tiles of 32, zero-padded
#define HID      256
#define DL       8
#define NC       48
#define CH       64
#define NCLS     10
#define T_ITERS  5
#define TILES    128        // B_N / 64

#define DT_      0.12f
#define CLAMP_   3.0f
#define GAIN_    0.06f
// b = log2(e)/(2*sigma_i^2) = 0.50093578 ; sigma_e = sigma_i/2 -> E-exp = 4x I-exp.
#define SQIL2    0.70776814f
#define ONE_BF16 0x3F80u

#if defined(__has_builtin)
#if __has_builtin(__builtin_amdgcn_exp2f)
#define EXP2(x) __builtin_amdgcn_exp2f(x)
#endif
#endif
#ifndef EXP2
#define EXP2(x) exp2f(x)
#endif

typedef __attribute__((ext_vector_type(8))) short short8v;  // 8 bf16 (4 VGPRs)
typedef __attribute__((ext_vector_type(4))) float f32x4;    // MFMA C/D frag

__device__ __forceinline__ unsigned int pack_bf16_rhu(float lo, float hi) {
    unsigned int b0 = __builtin_bit_cast(unsigned int, lo);
    unsigned int b1 = __builtin_bit_cast(unsigned int, hi);
    return ((b0 + 0x8000u) >> 16) | ((b1 + 0x8000u) & 0xFFFF0000u);
}
__device__ __forceinline__ unsigned short bf16_1(float x) {
    return (unsigned short)((__builtin_bit_cast(unsigned int, x) + 0x8000u) >> 16);
}
__device__ __forceinline__ float bf16_to_f(unsigned short h) {
    return __builtin_bit_cast(float, ((unsigned int)h) << 16);
}

// split one z row (scaled) into hi/lo bf16 + c constant pair (lateral path)
__device__ __forceinline__ void z_split(const float4 a, const float4 b,
                                        uint4& Whi, uint4& Wlo, unsigned int& Wc)
{
    float u[8] = {SQIL2*a.x, SQIL2*a.y, SQIL2*a.z, SQIL2*a.w,
                  SQIL2*b.x, SQIL2*b.y, SQIL2*b.z, SQIL2*b.w};
    float sq = 0.f;
    #pragma unroll
    for (int d = 0; d < 8; ++d) sq = fmaf(u[d], u[d], sq);
    float cn = -0.5f * sq;
    unsigned short hi[8]; float lo[8];
    #pragma unroll
    for (int d = 0; d < 8; ++d) {
        hi[d] = bf16_1(u[d]);
        lo[d] = u[d] - bf16_to_f(hi[d]);
    }
    unsigned short ch_ = bf16_1(cn);
    unsigned short cl_ = bf16_1(cn - bf16_to_f(ch_));
    Whi.x = (unsigned int)hi[0] | ((unsigned int)hi[1] << 16);
    Whi.y = (unsigned int)hi[2] | ((unsigned int)hi[3] << 16);
    Whi.z = (unsigned int)hi[4] | ((unsigned int)hi[5] << 16);
    Whi.w = (unsigned int)hi[6] | ((unsigned int)hi[7] << 16);
    Wlo.x = pack_bf16_rhu(lo[0], lo[1]); Wlo.y = pack_bf16_rhu(lo[2], lo[3]);
    Wlo.z = pack_bf16_rhu(lo[4], lo[5]); Wlo.w = pack_bf16_rhu(lo[6], lo[7]);
    Wc = (unsigned int)ch_ | ((unsigned int)cl_ << 16);
}

// 3-term bf16 split of 8 f32 values (24 mantissa bits -> near-exact)
__device__ __forceinline__ void split3_8(const float v[8],
                                         uint4& Th, uint4& Tm, uint4& Tl)
{
    unsigned short h8[8], m8[8], l8[8];
    #pragma unroll
    for (int d = 0; d < 8; ++d) {
        unsigned short h = bf16_1(v[d]);
        float r1 = v[d] - bf16_to_f(h);
        unsigned short m = bf16_1(r1);
        float r2 = r1 - bf16_to_f(m);
        unsigned short l = bf16_1(r2);
        h8[d] = h; m8[d] = m; l8[d] = l;
    }
    Th.x = (unsigned int)h8[0] | ((unsigned int)h8[1] << 16);
    Th.y = (unsigned int)h8[2] | ((unsigned int)h8[3] << 16);
    Th.z = (unsigned int)h8[4] | ((unsigned int)h8[5] << 16);
    Th.w = (unsigned int)h8[6] | ((unsigned int)h8[7] << 16);
    Tm.x = (unsigned int)m8[0] | ((unsigned int)m8[1] << 16);
    Tm.y = (unsigned int)m8[2] | ((unsigned int)m8[3] << 16);
    Tm.z = (unsigned int)m8[4] | ((unsigned int)m8[5] << 16);
    Tm.w = (unsigned int)m8[6] | ((unsigned int)m8[7] << 16);
    Tl.x = (unsigned int)l8[0] | ((unsigned int)l8[1] << 16);
    Tl.y = (unsigned int)l8[2] | ((unsigned int)l8[3] << 16);
    Tl.z = (unsigned int)l8[4] | ((unsigned int)l8[5] << 16);
    Tl.w = (unsigned int)l8[6] | ((unsigned int)l8[7] << 16);
}

// ============ one-time: W1 -> transposed 3-term bf16, k padded to 800 ========
__global__ __launch_bounds__(256) void k_w1split(
    const float* __restrict__ W1, unsigned short* __restrict__ W1aT,
    unsigned short* __restrict__ W1bT, unsigned short* __restrict__ W1cT)
{
    const int k = blockIdx.x;        // 0..799
    const int n = threadIdx.x;       // 0..255
    float v = (k < IN_DIM) ? W1[(size_t)k * HID + n] : 0.f;
    unsigned short h = bf16_1(v);
    float r1 = v - bf16_to_f(h);
    unsigned short m = bf16_1(r1);
    unsigned short l = bf16_1(r1 - bf16_to_f(m));
    W1aT[(size_t)n * KPAD + k] = h;
    W1bT[(size_t)n * KPAD + k] = m;
    W1cT[(size_t)n * KPAD + k] = l;
}

// ============ encoder GEMM1 via MFMA (3-term bf16 split, f32 accum) ==========
__global__ __launch_bounds__(256, 2) void k_gemm1_tanh(
    const float* __restrict__ x, const unsigned short* __restrict__ W1aT,
    const unsigned short* __restrict__ W1bT, const unsigned short* __restrict__ W1cT,
    const float* __restrict__ b1, float* __restrict__ H1)
{
    __shared__ __align__(16) unsigned short Ah[2][64][40], Am[2][64][40], Al[2][64][40];
    __shared__ __align__(16) unsigned short Bh[2][64][40], Bm[2][64][40], Bl[2][64][40];
    const int tid = threadIdx.x;
    const int row0 = blockIdx.x * 64;
    const int col0 = blockIdx.y * 64;
    const int wv = tid >> 6, lane = tid & 63;
    const int l15 = lane & 15, g = lane >> 4;
    const int sr = tid >> 2, ss = tid & 3;

    f32x4 acc[4] = {{0,0,0,0},{0,0,0,0},{0,0,0,0},{0,0,0,0}};

    {
        float xv[8];
        {
            const float* xp = x + (size_t)(row0 + sr) * IN_DIM + ss * 8;
            float4 a = *(const float4*)(xp), b = *(const float4*)(xp + 4);
            xv[0]=a.x; xv[1]=a.y; xv[2]=a.z; xv[3]=a.w;
            xv[4]=b.x; xv[5]=b.y; xv[6]=b.z; xv[7]=b.w;
        }
        uint4 Th, Tm, Tl;
        split3_8(xv, Th, Tm, Tl);
        *(uint4*)&Ah[0][sr][ss * 8] = Th;
        *(uint4*)&Am[0][sr][ss * 8] = Tm;
        *(uint4*)&Al[0][sr][ss * 8] = Tl;
        const size_t wo = (size_t)(col0 + sr) * KPAD + ss * 8;
        *(uint4*)&Bh[0][sr][ss * 8] = *(const uint4*)(W1aT + wo);
        *(uint4*)&Bm[0][sr][ss * 8] = *(const uint4*)(W1bT + wo);
        *(uint4*)&Bl[0][sr][ss * 8] = *(const uint4*)(W1cT + wo);
    }

    const int NK = KPAD / 32;   // 25
    #pragma unroll 1
    for (int ks = 0; ks < NK; ++ks) {
        const int cur = ks & 1;
        const bool more = (ks + 1 < NK);
        float xv[8];
        uint4 wa4, wb4, wc4;
        if (more) {
            const int k0 = (ks + 1) * 32;
            if (k0 + ss * 8 < IN_DIM) {
                const float* xp = x + (size_t)(row0 + sr) * IN_DIM + k0 + ss * 8;
                float4 a = *(const float4*)(xp), b = *(const float4*)(xp + 4);
                xv[0]=a.x; xv[1]=a.y; xv[2]=a.z; xv[3]=a.w;
                xv[4]=b.x; xv[5]=b.y; xv[6]=b.z; xv[7]=b.w;
            } else {
                #pragma unroll
                for (int d = 0; d < 8; ++d) xv[d] = 0.f;
            }
            const size_t wo = (size_t)(col0 + sr) * KPAD + k0 + ss * 8;
            wa4 = *(const uint4*)(W1aT + wo);
            wb4 = *(const uint4*)(W1bT + wo);
            wc4 = *(const uint4*)(W1cT + wo);
        }
        __syncthreads();

        short8v ah = *(const short8v*)&Ah[cur][16 * wv + l15][g * 8];
        short8v am = *(const short8v*)&Am[cur][16 * wv + l15][g * 8];
        short8v al = *(const short8v*)&Al[cur][16 * wv + l15][g * 8];
        __builtin_amdgcn_s_setprio(1);
        #pragma unroll
        for (int nt = 0; nt < 4; ++nt) {
            short8v bh = *(const short8v*)&Bh[cur][nt * 16 + l15][g * 8];
            short8v bm = *(const short8v*)&Bm[cur][nt * 16 + l15][g * 8];
            short8v bl = *(const short8v*)&Bl[cur][nt * 16 + l15][g * 8];
            acc[nt] = __builtin_amdgcn_mfma_f32_16x16x32_bf16(ah, bh, acc[nt], 0, 0, 0);
            acc[nt] = __builtin_amdgcn_mfma_f32_16x16x32_bf16(am, bh, acc[nt], 0, 0, 0);
            acc[nt] = __builtin_amdgcn_mfma_f32_16x16x32_bf16(ah, bm, acc[nt], 0, 0, 0);
            acc[nt] = __builtin_amdgcn_mfma_f32_16x16x32_bf16(al, bh, acc[nt], 0, 0, 0);
            acc[nt] = __builtin_amdgcn_mfma_f32_16x16x32_bf16(am, bm, acc[nt], 0, 0, 0);
            acc[nt] = __builtin_amdgcn_mfma_f32_16x16x32_bf16(ah, bl, acc[nt], 0, 0, 0);
        }
        __builtin_amdgcn_s_setprio(0);

        if (more) {
            const int nb = cur ^ 1;
            uint4 Th, Tm, Tl;
            split3_8(xv, Th, Tm, Tl);
            *(uint4*)&Ah[nb][sr][ss * 8] = Th;
            *(uint4*)&Am[nb][sr][ss * 8] = Tm;
            *(uint4*)&Al[nb][sr][ss * 8] = Tl;
            *(uint4*)&Bh[nb][sr][ss * 8] = wa4;
            *(uint4*)&Bm[nb][sr][ss * 8] = wb4;
            *(uint4*)&Bl[nb][sr][ss * 8] = wc4;
        }
    }

    #pragma unroll
    for (int nt = 0; nt < 4; ++nt) {
        const int cc = col0 + nt * 16 + l15;
        const float bc = b1[cc];
        #pragma unroll
        for (int r = 0; r < 4; ++r) {
            const int rr = row0 + 16 * wv + g * 4 + r;
            H1[(size_t)rr * HID + cc] = tanhf(acc[nt][r] + bc);
        }
    }
}

// ============ PM field + fused z0-GEMM (t==0) + partial-reduce + proj ========
// 16 lanes/row (3 centers/lane). Exact IEEE sqrt/divide in the stiff flow.
// HP=false additionally computes z0 = H1 @ W2 + b2 for its own 16 rows
// (bit-identical to the old k_gemm2: same thread mapping, same k-order).
template<int S, bool HP>
__global__ __launch_bounds__(256) void k_pm_proj(
    const float* __restrict__ H1, const float* __restrict__ W2,
    const float* __restrict__ b2,
    const float* __restrict__ centers, const float* __restrict__ mus,
    const float* __restrict__ projW, const float* __restrict__ projb,
    float* __restrict__ zbuf, float* __restrict__ hB,
    unsigned short* __restrict__ hTb, unsigned short* __restrict__ zAg,
    const float* __restrict__ pAcc, const float* __restrict__ pDen)
{
    __shared__ float4 cs4[NC][2];
    __shared__ float mu_s[NC];
    __shared__ float pW[DL][CH];
    __shared__ float pb[CH];
    __shared__ float W2s[HID][DL];   // t==0 only
    __shared__ float zsh[16][DL];    // t==0 only
    const int tid = threadIdx.x;
    for (int l = tid; l < NC * 2; l += 256) cs4[l >> 1][l & 1] = ((const float4*)centers)[l];
    if (tid < NC) mu_s[tid] = mus[tid];
    for (int l = tid; l < DL * CH; l += 256) pW[l >> 6][l & 63] = projW[l];
    if (tid < CH) pb[tid] = projb[tid];

    const int rloc = tid >> 4;
    const int ln   = tid & 15;
    const int row  = blockIdx.x * 16 + rloc;

    if (!HP) {   // ---- fused gemm2 for this block's 16 rows ----
        for (int l = tid; l < HID * DL; l += 256) W2s[l >> 3][l & 7] = W2[l];
        __syncthreads();
        if (tid < 128) {
            const int grow = blockIdx.x * 16 + (tid >> 3);
            const int d = tid & 7;
            float acc = b2[d];
            const float* hr = H1 + (size_t)grow * HID;
            for (int k = 0; k < HID; k += 4) {
                float4 hv = *(const float4*)(hr + k);
                acc += hv.x * W2s[k][d] + hv.y * W2s[k+1][d]
                     + hv.z * W2s[k+2][d] + hv.w * W2s[k+3][d];
            }
            zsh[tid >> 3][d] = acc;
        }
    }
    __syncthreads();

    float4 cza[3], czb[3];
    float mur[3];
    #pragma unroll
    for (int k = 0; k < 3; ++k) {
        cza[k] = cs4[ln + 16*k][0];
        czb[k] = cs4[ln + 16*k][1];
        mur[k] = mu_s[ln + 16*k];
    }

    float z[8];
    if (!HP) {
        #pragma unroll
        for (int d = 0; d < 8; ++d) z[d] = zsh[rloc][d];
    } else {
        const float4* zp = (const float4*)(zbuf + (size_t)row * DL);
        float4 a = zp[0], b = zp[1];
        z[0]=a.x; z[1]=a.y; z[2]=a.z; z[3]=a.w;
        z[4]=b.x; z[5]=b.y; z[6]=b.z; z[7]=b.w;
    }

    #pragma unroll
    for (int step = 0; step < 4; ++step) {
        float np = 0.f;
        float gp[8] = {0,0,0,0,0,0,0,0};
        #pragma unroll
        for (int k = 0; k < 3; ++k) {
            float d0 = z[0]-cza[k].x, d1 = z[1]-cza[k].y;
            float d2 = z[2]-cza[k].z, d3 = z[3]-cza[k].w;
            float d4 = z[4]-czb[k].x, d5 = z[5]-czb[k].y;
            float d6 = z[6]-czb[k].z, d7 = z[7]-czb[k].w;
            float r2 = 1e-4f;
            r2 = fmaf(d0,d0,r2); r2 = fmaf(d1,d1,r2);
            r2 = fmaf(d2,d2,r2); r2 = fmaf(d3,d3,r2);
            r2 = fmaf(d4,d4,r2); r2 = fmaf(d5,d5,r2);
            r2 = fmaf(d6,d6,r2); r2 = fmaf(d7,d7,r2);
            float r = sqrtf(r2);
            float mr = mur[k] / r;
            np += mr;
            float tt = mr / r2;
            gp[0] = fmaf(-tt, d0, gp[0]); gp[1] = fmaf(-tt, d1, gp[1]);
            gp[2] = fmaf(-tt, d2, gp[2]); gp[3] = fmaf(-tt, d3, gp[3]);
            gp[4] = fmaf(-tt, d4, gp[4]); gp[5] = fmaf(-tt, d5, gp[5]);
            gp[6] = fmaf(-tt, d6, gp[6]); gp[7] = fmaf(-tt, d7, gp[7]);
        }
        #pragma unroll
        for (int m = 1; m < 16; m <<= 1) {
            np += __shfl_xor(np, m);
            #pragma unroll
            for (int d = 0; d < 8; ++d) gp[d] += __shfl_xor(gp[d], m);
        }
        float s = DT_ / (1.f + np);
        #pragma unroll
        for (int d = 0; d < 8; ++d) {
            z[d] = fmaf(s, gp[d], z[d]);
            z[d] = fminf(fmaxf(z[d], -CLAMP_), CLAMP_);
        }
    }

    if (ln < 8) {
        float zout = z[0];
        #pragma unroll
        for (int d = 1; d < 8; ++d) zout = (ln == d) ? z[d] : zout;
        zbuf[(size_t)row * DL + ln] = zout;
    }

    // emit zAg (j-form: [hi8 | lo8 | ch,cl,1,1,0,0,0,0])
    if (ln < 3) {
        float4 a4 = {z[0], z[1], z[2], z[3]};
        float4 b4 = {z[4], z[5], z[6], z[7]};
        uint4 Whi, Wlo; unsigned int Wc;
        z_split(a4, b4, Whi, Wlo, Wc);
        uint4 Wa; Wa.x = Wc; Wa.y = ONE_BF16 | (ONE_BF16 << 16); Wa.z = 0; Wa.w = 0;
        uint4 outv = (ln == 0) ? Whi : ((ln == 1) ? Wlo : Wa);
        *(uint4*)(zAg + (size_t)row * 24 + ln * 8) = outv;
    }

    const int c0 = ln * 4;
    float hin[4];
    if (HP) {
        float den = 1e-6f;
        #pragma unroll
        for (int s = 0; s < S; ++s) den += pDen[s * B_N + row];
        float inv = GAIN_ / den;
        float4 a = {0.f, 0.f, 0.f, 0.f};
        #pragma unroll
        for (int s = 0; s < S; ++s) {
            float4 p = *(const float4*)(pAcc + (size_t)s * B_N * CH
                                        + (size_t)row * CH + c0);
            a.x += p.x; a.y += p.y; a.z += p.z; a.w += p.w;
        }
        float4 hm = *(const float4*)(hB + (size_t)row * CH + c0);
        hin[0] = fmaf(inv, a.x, hm.x);
        hin[1] = fmaf(inv, a.y, hm.y);
        hin[2] = fmaf(inv, a.z, hm.z);
        hin[3] = fmaf(inv, a.w, hm.w);
    } else {
        #pragma unroll
        for (int k = 0; k < 4; ++k) hin[k] = 0.f;
    }
    #pragma unroll
    for (int k = 0; k < 4; ++k) {
        int c = c0 + k;
        float s = pb[c];
        #pragma unroll
        for (int dd = 0; dd < DL; ++dd) s = fmaf(z[dd], pW[dd][c], s);
        hin[k] = 0.9f * hin[k] + 0.1f * tanhf(s);
    }
    float4 o0 = {hin[0], hin[1], hin[2], hin[3]};
    *(float4*)(hB + (size_t)row * CH + c0) = o0;

    {
        const int jl = row & 63;
        const int colp = (jl & 35) | ((jl & 12) << 1) | ((jl & 16) >> 2);
        const size_t tb = (size_t)(row & ~63) + colp;
        #pragma unroll
        for (int k = 0; k < 4; ++k)
            hTb[(size_t)(c0 + k) * B_N + tb] = bf16_1(hin[k]);
    }
}

// ============ lateral EI: Gram-MFMA weights + MFMA K@h ============
// Gram + exp/pack are register-only -> hoisted ABOVE the per-tile barrier
// (barrier only orders hsT). K@h reads hsT[cur] after the barrier.
template<int S>
__global__ __launch_bounds__(256, 4) void k_lateral(
    const unsigned short* __restrict__ zAg, const unsigned short* __restrict__ hTb,
    float* __restrict__ pAcc, float* __restrict__ pDen)
{
    __shared__ __align__(16) unsigned short hsT[2][CH][72];
    const int tid  = threadIdx.x;
    const int lane = tid & 63;
    const int wv   = tid >> 6;
    const int l15  = lane & 15;
    const int g    = lane >> 4;
    const int rowbase = blockIdx.x * 64;
    const int t0 = (TILES * blockIdx.y) / S;
    const int t1 = (TILES * (blockIdx.y + 1)) / S;
    const int chS = tid >> 2, segS = tid & 3;

    union u4s8 { uint4 u; short8v v; };

    short8v bZ;
    {
        const int bsel = (g == 2) ? 1 : ((g == 3) ? 2 : 0);
        u4s8 b4;
        b4.u = *(const uint4*)(zAg + (size_t)(rowbase + 16 * wv + l15) * 24 + bsel * 8);
        if (g == 3) { unsigned int t_ = b4.u.x; b4.u.x = b4.u.y; b4.u.y = t_; }
        bZ = b4.v;
    }
    const int asel = (g == 1) ? 1 : ((g == 3) ? 2 : 0);

    short8v bones;
    {
        u4s8 uo;
        uo.u.x = uo.u.y = uo.u.z = uo.u.w = ONE_BF16 | (ONE_BF16 << 16);
        bones = uo.v;
    }

    f32x4 acc0 = {0,0,0,0}, acc1 = {0,0,0,0}, acc2 = {0,0,0,0}, acc3 = {0,0,0,0};
    f32x4 acc4 = {0,0,0,0};
    const f32x4 zc = {0,0,0,0};

    uint4 az4[4];
    {
        const int jb = t0 * 64;
        #pragma unroll
        for (int tt = 0; tt < 4; ++tt)
            az4[tt] = *(const uint4*)(zAg + (size_t)(jb + tt * 16 + l15) * 24 + asel * 8);
        const unsigned short* hs = hTb + (size_t)chS * B_N + jb + segS * 16;
        *(uint4*)(&hsT[0][chS][segS * 16])     = *(const uint4*)(hs);
        *(uint4*)(&hsT[0][chS][segS * 16 + 8]) = *(const uint4*)(hs + 8);
    }

    #pragma unroll 1
    for (int jt = t0; jt < t1; ++jt) {
        const int cur = (jt - t0) & 1;
        const bool more = (jt + 1 < t1);
        uint4 h0n, h1n, azn0, azn1, azn2, azn3;
        if (more) {
            const int jb2 = (jt + 1) * 64;
            const unsigned short* hs = hTb + (size_t)chS * B_N + jb2 + segS * 16;
            h0n = *(const uint4*)(hs);
            h1n = *(const uint4*)(hs + 8);
            azn0 = *(const uint4*)(zAg + (size_t)(jb2 +  0 + l15) * 24 + asel * 8);
            azn1 = *(const uint4*)(zAg + (size_t)(jb2 + 16 + l15) * 24 + asel * 8);
            azn2 = *(const uint4*)(zAg + (size_t)(jb2 + 32 + l15) * 24 + asel * 8);
            azn3 = *(const uint4*)(zAg + (size_t)(jb2 + 48 + l15) * 24 + asel * 8);
        }

        // ---- Gram (register-only): BEFORE the barrier ----
        f32x4 gac[4];
        __builtin_amdgcn_s_setprio(1);
        #pragma unroll
        for (int tt = 0; tt < 4; ++tt) {
            u4s8 az; az.u = az4[tt];
            gac[tt] = __builtin_amdgcn_mfma_f32_16x16x32_bf16(az.v, bZ, zc, 0, 0, 0);
        }
        __builtin_amdgcn_s_setprio(0);

        // ---- w path (register-only): BEFORE the barrier ----
        short8v afr[2];
        #pragma unroll
        for (int kb = 0; kb < 2; ++kb) {
            float w8[8];
            #pragma unroll
            for (int m = 0; m < 8; ++m) {
                float out = gac[2 * kb + (m >> 2)][m & 3];
                float e1 = EXP2(out);
                float e2 = e1 * e1;
                float e4 = e2 * e2;
                float e8 = e4 * e4;
                w8[m] = fmaf(0.8f, e8, -e2);
            }
            u4s8 uf;
            uf.u.x = pack_bf16_rhu(w8[0], w8[1]);
            uf.u.y = pack_bf16_rhu(w8[2], w8[3]);
            uf.u.z = pack_bf16_rhu(w8[4], w8[5]);
            uf.u.w = pack_bf16_rhu(w8[6], w8[7]);
            afr[kb] = uf.v;
        }

        __syncthreads();   // hsT[cur] writes (prev iter) visible

        // ---- K@h + den (reads hsT[cur]) ----
        __builtin_amdgcn_s_setprio(1);
        #pragma unroll
        for (int kb = 0; kb < 2; ++kb) {
            const int jo = kb * 32 + g * 8;
            short8v b0 = *(const short8v*)&hsT[cur][ 0 + l15][jo];
            short8v b1 = *(const short8v*)&hsT[cur][16 + l15][jo];
            short8v b2 = *(const short8v*)&hsT[cur][32 + l15][jo];
            short8v b3 = *(const short8v*)&hsT[cur][48 + l15][jo];
            acc0 = __builtin_amdgcn_mfma_f32_16x16x32_bf16(afr[kb], b0, acc0, 0, 0, 0);
            acc1 = __builtin_amdgcn_mfma_f32_16x16x32_bf16(afr[kb], b1, acc1, 0, 0, 0);
            acc2 = __builtin_amdgcn_mfma_f32_16x16x32_bf16(afr[kb], b2, acc2, 0, 0, 0);
            acc3 = __builtin_amdgcn_mfma_f32_16x16x32_bf16(afr[kb], b3, acc3, 0, 0, 0);
            acc4 = __builtin_amdgcn_mfma_f32_16x16x32_bf16(afr[kb], bones, acc4, 0, 0, 0);
        }
        __builtin_amdgcn_s_setprio(0);

        if (more) {   // hsT[nb] write (no 2nd barrier: nobody reads nb yet)
            const int nb = cur ^ 1;
            *(uint4*)(&hsT[nb][chS][segS * 16])     = h0n;
            *(uint4*)(&hsT[nb][chS][segS * 16 + 8]) = h1n;
            az4[0] = azn0; az4[1] = azn1; az4[2] = azn2; az4[3] = azn3;
        }
    }

    float* pA = pAcc + (size_t)blockIdx.y * (B_N * CH) + (size_t)rowbase * CH;
    #pragma unroll
    for (int r = 0; r < 4; ++r) {
        int gi = 16 * wv + g * 4 + r;
        pA[(size_t)gi * CH +  0 + l15] = acc0[r];
        pA[(size_t)gi * CH + 16 + l15] = acc1[r];
        pA[(size_t)gi * CH + 32 + l15] = acc2[r];
        pA[(size_t)gi * CH + 48 + l15] = acc3[r];
    }
    if (l15 == 0) {
        #pragma unroll
        for (int r = 0; r < 4; ++r)
            pDen[blockIdx.y * B_N + rowbase + 16 * wv + g * 4 + r] = acc4[r];
    }
}

// ============ final: h = hmid + GAIN*acc/den ; logits = h @ roW + rob ======
template<int S>
__global__ __launch_bounds__(256) void k_logits_h(
    const float* __restrict__ hmid, const float* __restrict__ pAcc,
    const float* __restrict__ pDen, const float* __restrict__ roW,
    const float* __restrict__ rob, float* __restrict__ out_logits,
    float* __restrict__ out_h)
{
    __shared__ float hsh[64][68];
    __shared__ float ro[CH][NCLS];
    __shared__ float rb[NCLS];
    const int tid = threadIdx.x;
    for (int l = tid; l < CH * NCLS; l += 256) ro[l / NCLS][l % NCLS] = roW[l];
    if (tid < NCLS) rb[tid] = rob[tid];
    const int rowbase = blockIdx.x * 64;
    const int r  = tid >> 2;
    const int c0 = (tid & 3) * 16;
    const int row = rowbase + r;
    float den = 1e-6f;
    #pragma unroll
    for (int s = 0; s < S; ++s) den += pDen[s * B_N + row];
    float inv = GAIN_ / den;
    #pragma unroll
    for (int q = 0; q < 4; ++q) {
        float4 a = {0.f, 0.f, 0.f, 0.f};
        #pragma unroll
        for (int s = 0; s < S; ++s) {
            float4 p = *(const float4*)(pAcc + (size_t)s * B_N * CH
                                        + (size_t)row * CH + c0 + q * 4);
            a.x += p.x; a.y += p.y; a.z += p.z; a.w += p.w;
        }
        float4 hm = *(const float4*)(hmid + (size_t)row * CH + c0 + q * 4);
        float4 hv;
        hv.x = fmaf(inv, a.x, hm.x); hv.y = fmaf(inv, a.y, hm.y);
        hv.z = fmaf(inv, a.z, hm.z); hv.w = fmaf(inv, a.w, hm.w);
        *(float4*)(&hsh[r][c0 + q * 4]) = hv;
        *(float4*)(out_h + (size_t)row * CH + c0 + q * 4) = hv;
    }
    __syncthreads();
    for (int idx = tid; idx < 64 * NCLS; idx += 256) {
        int rr = idx / NCLS, o = idx % NCLS;
        float s = rb[o];
        #pragma unroll
        for (int k = 0; k < CH; ++k) s = fmaf(hsh[rr][k], ro[k][o], s);
        out_logits[(size_t)(rowbase + rr) * NCLS + o] = s;
    }
}

// ---- per-split launch helper ----
template<int S>
static void run_all(const float* x, const float* W1, const float* b1,
                    const float* W2, const float* b2, const float* centers,
                    const float* mus, const float* projW, const float* projb,
                    const float* roW, const float* rob,
                    float* ws, float* out, hipStream_t stream)
{
    float* pAcc = ws;
    float* pDen = ws + (size_t)S * B_N * CH;
    float* zbuf = pDen + (size_t)S * B_N;
    float* hB   = zbuf + B_N * DL;
    unsigned short* hTb  = (unsigned short*)(hB + B_N * CH);
    unsigned short* zAg  = hTb + (size_t)B_N * CH;
    unsigned short* W1aT = zAg + (size_t)B_N * 24;
    unsigned short* W1bT = W1aT + (size_t)HID * KPAD;
    unsigned short* W1cT = W1bT + (size_t)HID * KPAD;
    float* H1 = (float*)(W1cT + (size_t)HID * KPAD);

    float* out_logits = out;
    float* out_z      = out + 81920;
    float* out_h      = out_z + 65536;

    k_w1split<<<KPAD, HID, 0, stream>>>(W1, W1aT, W1bT, W1cT);
    k_gemm1_tanh<<<dim3(B_N / 64, HID / 64), 256, 0, stream>>>(x, W1aT, W1bT, W1cT, b1, H1);

    for (int t = 0; t < T_ITERS; ++t) {
        if (t == 0)
            k_pm_proj<S, false><<<B_N / 16, 256, 0, stream>>>(
                H1, W2, b2, centers, mus, projW, projb,
                zbuf, hB, hTb, zAg, pAcc, pDen);
        else
            k_pm_proj<S, true><<<B_N / 16, 256, 0, stream>>>(
                H1, W2, b2, centers, mus, projW, projb,
                zbuf, hB, hTb, zAg, pAcc, pDen);
        k_lateral<S><<<dim3(TILES, S), 256, 0, stream>>>(zAg, hTb, pAcc, pDen);
    }

    k_logits_h<S><<<TILES, 256, 0, stream>>>(hB, pAcc, pDen, roW, rob,
                                             out_logits, out_h);
    hipMemcpyAsync(out_z, zbuf, (size_t)B_N * DL * sizeof(float),
                   hipMemcpyDeviceToDevice, stream);
}

extern "C" void kernel_launch(void* const* d_in, const int* in_sizes, int n_in,
                              void* d_out, int out_size, void* d_ws, size_t ws_size,
                              hipStream_t stream)
{
    const float* x       = (const float*)d_in[0];
    const float* W1      = (const float*)d_in[1];
    const float* b1      = (const float*)d_in[2];
    const float* W2      = (const float*)d_in[3];
    const float* b2      = (const float*)d_in[4];
    const float* centers = (const float*)d_in[5];
    const float* mus     = (const float*)d_in[6];
    const float* projW   = (const float*)d_in[7];
    const float* projb   = (const float*)d_in[8];
    const float* roW     = (const float*)d_in[9];
    const float* rob     = (const float*)d_in[10];

    float* ws  = (float*)d_ws;
    float* out = (float*)d_out;

    const size_t extraW = (size_t)B_N * 12 + (size_t)3 * HID * KPAD / 2 + (size_t)B_N * HID;
    const size_t needS8 = ((size_t)8*B_N*CH + 8*B_N + B_N*DL + B_N*CH + B_N*CH/2 + extraW) * 4;
    const size_t needS4 = ((size_t)4*B_N*CH + 4*B_N + B_N*DL + B_N*CH + B_N*CH/2 + extraW) * 4;

    if (ws_size >= needS8)
        run_all<8>(x, W1, b1, W2, b2, centers, mus, projW, projb, roW, rob, ws, out, stream);
    else if (ws_size >= needS4)
        run_all<4>(x, W1, b1, W2, b2, centers, mus, projW, projb, roW, rob, ws, out, stream);
    else
        run_all<2>(x, W1, b1, W2, b2, centers, mus, projW, projb, roW, rob, ws, out, stream);
}